// Round 1
// baseline (484.796 us; speedup 1.0000x reference)
//
#include <hip/hip_runtime.h>
#include <cstdint>
#include <cstddef>

// ============================================================================
// ProposedConv hypergraph dual-attention, restructured:
//  - A=(H@H^T>0) via per-edge clique bit-scatter (no NxN GEMM)
//  - attention_g never normalized standalone: expA (unnormalized, bf16) @
//    [H | Wh_g] with 1/rowsum epilogue -> graph2hyper + attention_g@Wh_g
//  - att2he@att2he^T@Wh_g and att2hn@att2hn^T@Wh_g factored into thin GEMMs
//  - all GEMMs: bf16 MFMA 16x16x32, NT layout, global_load_lds(16B) staging
//    with XOR chunk swizzle (staging must be lane-contiguous; swizzle makes
//    ds_read_b128 frag loads <=2-way bank conflicted = free)
// ============================================================================

#define DI __device__ __forceinline__
typedef unsigned short u16;
typedef unsigned int   u32;
typedef __bf16 bf16x8 __attribute__((ext_vector_type(8)));
typedef float  f32x4  __attribute__((ext_vector_type(4)));

constexpr int NN  = 4096;   // nodes
constexpr int EE  = 2048;   // hyperedges
constexpr int DD  = 256;    // feature dim
constexpr int NNZb = 65536; // incidence nnz

// ---------------- workspace layout (bytes), peak 127 MB ----------------
constexpr size_t MB = (size_t)1 << 20;
constexpr size_t OFF_HBITS   = 0;          // u32 [4096][64]
constexpr size_t OFF_HBITST  = 1*MB;       // u32 [2048][128]
constexpr size_t OFF_ABITS   = 2*MB;       // u32 [4096][128]
constexpr size_t OFF_WH1     = 4*MB;              // f32 [4096]
constexpr size_t OFF_WH2     = 4*MB + 16384;      // f32 [4096]
constexpr size_t OFF_V       = 4*MB + 32768;      // f32 [4096]
constexpr size_t OFF_RSINV   = 4*MB + 49152;      // f32 [4096]
constexpr size_t OFF_WCATT   = 5*MB;       // bf16 [1024][256]  (wgT|w2T|w1T|w3T)
constexpr size_t OFF_XB      = 6*MB;       // bf16 [4096][256]
constexpr size_t OFF_WHG     = 8*MB;       // bf16 [4096][256]
constexpr size_t OFF_X4ATT   = 10*MB;      // bf16 [4096][256]
constexpr size_t OFF_XW      = 12*MB;      // bf16 [4096][256]
constexpr size_t OFF_XWT     = 14*MB;      // bf16 [256][4096]  (xwT ; whgT contiguous)
constexpr size_t OFF_WHGT1   = 16*MB;      // bf16 [256][4096]
constexpr size_t OFF_HBT     = 18*MB;      // bf16 [2048][4096] (H^T ; whgT2 contiguous)
constexpr size_t OFF_WHGT2   = 34*MB;      // bf16 [256][4096]
constexpr size_t OFF_EXPA    = 36*MB;      // bf16 [4096][4096] (dead after big GEMM)
constexpr size_t OFF_ATT1    = 36*MB;      //   then bf16 [2048][4096]
constexpr size_t OFF_ATT2HN  = 36*MB;      //   then bf16 [4096][2048] (att1 dead)
constexpr size_t OFF_ATT1T   = 52*MB;      // bf16 [4096][2048]
constexpr size_t OFF_G2H     = 68*MB;      // bf16 [4096][2048]
constexpr size_t OFF_G2HT    = 84*MB;      // bf16 [2048][4096]; att2hnT reuses
constexpr size_t OFF_ATT2HNT = 84*MB;
constexpr size_t OFF_ATTN2   = 100*MB;     // bf16 [4096][2048]; C1/C2 reuse
constexpr size_t OFF_C1      = 100*MB;     // f32 [4096][512]
constexpr size_t OFF_C2      = 108*MB;     // f32 [4096][256]
constexpr size_t OFF_G1      = 116*MB;     // f32 [4096][256]
constexpr size_t OFF_EDGE    = 120*MB;     // bf16 [2048][256]
constexpr size_t OFF_EDGE2   = 121*MB;
constexpr size_t OFF_E4ATT   = 122*MB;
constexpr size_t OFF_HN2     = 123*MB;
constexpr size_t OFF_EDGET   = 124*MB;     // bf16 [256][2048] (edgeT ; hn2T contiguous)
constexpr size_t OFF_HN2T    = 125*MB;
constexpr size_t OFF_EDGE2T  = 126*MB;

// ---------------- helpers ----------------
DI u16 to_bf(float f) {                 // round-to-nearest-even f32->bf16
  union { float f; u32 u; } x; x.f = f;
  u32 r = x.u + 0x7fffu + ((x.u >> 16) & 1u);
  return (u16)(r >> 16);
}
DI float from_bf(u16 h) { union { u32 u; float f; } x; x.u = (u32)h << 16; return x.f; }

DI float wredf(float v) {
  #pragma unroll
  for (int o = 32; o; o >>= 1) v += __shfl_down(v, o);
  return v;
}
DI int wredi(int v) {
  #pragma unroll
  for (int o = 32; o; o >>= 1) v += __shfl_down(v, o);
  return v;
}

typedef __attribute__((address_space(3))) void lds_void;
typedef __attribute__((address_space(1))) void glb_void;
DI void async_load16(const void* g, void* l) {
  // direct global->LDS DMA; HW writes lane i at (uniform lds base) + i*16
  __builtin_amdgcn_global_load_lds((glb_void*)(uintptr_t)g,
                                   (lds_void*)(u32)(uintptr_t)l, 16, 0, 0);
}

// ---------------- generic NT bf16 GEMM: C[m][n] = sum_k A[m][k]*B[n][k] ----
// A:[M,K] B:[N,K] row-major bf16, K%64==0, M%BM==0, N%BN==0.
template <int BM, int BN, class Epi>
__global__ __launch_bounds__(256, 2)
void gemm_nt(const u16* __restrict__ A, const u16* __restrict__ B,
             int N, int K, Epi epi)
{
  constexpr int BK = 64;
  constexpr int WM = BM / 2, WN = BN / 2;
  constexpr int FM = WM / 16, FN = WN / 16;
  constexpr int AI = (BM * 8) / 256, BI = (BN * 8) / 256;   // 16B chunks / thread
  __shared__ __align__(16) u16 As[BM * BK];
  __shared__ __align__(16) u16 Bs[BN * BK];

  const int tid = threadIdx.x;
  const int w = tid >> 6, l = tid & 63;
  const int nb = N / BN;
  const int bi = blockIdx.x / nb, bj = blockIdx.x - bi * nb;
  const int i0 = bi * BM, j0 = bj * BN;
  const int wm = (w & 1) * WM, wn = (w >> 1) * WN;
  const int quad = l >> 4, m16 = l & 15;

  f32x4 acc[FM][FN] = {};

  for (int kb = 0; kb < K; kb += BK) {
    __syncthreads();                       // protect LDS from previous compute
    #pragma unroll
    for (int i = 0; i < AI; ++i) {
      const int ci = (i * 4 + w) * 64 + l; // chunk id, LDS dest = ci*16 bytes
      const int r = ci >> 3;
      const int lc = (ci & 7) ^ (r & 7);   // XOR swizzle: logical k-chunk
      async_load16(A + (size_t)(i0 + r) * K + kb + lc * 8, &As[(i * 4 + w) * 512]);
    }
    #pragma unroll
    for (int i = 0; i < BI; ++i) {
      const int ci = (i * 4 + w) * 64 + l;
      const int r = ci >> 3;
      const int lc = (ci & 7) ^ (r & 7);
      async_load16(B + (size_t)(j0 + r) * K + kb + lc * 8, &Bs[(i * 4 + w) * 512]);
    }
    __syncthreads();                       // compiler drains vmcnt before barrier
    #pragma unroll
    for (int ks = 0; ks < 2; ++ks) {
      bf16x8 af[FM], bfv[FN];
      #pragma unroll
      for (int mi = 0; mi < FM; ++mi) {
        const int row = wm + mi * 16 + m16;
        const int off = row * BK + (((ks * 4 + quad) ^ (row & 7)) * 8);
        af[mi] = *(const bf16x8*)&As[off];
      }
      #pragma unroll
      for (int ni = 0; ni < FN; ++ni) {
        const int row = wn + ni * 16 + m16;
        const int off = row * BK + (((ks * 4 + quad) ^ (row & 7)) * 8);
        bfv[ni] = *(const bf16x8*)&Bs[off];
      }
      #pragma unroll
      for (int mi = 0; mi < FM; ++mi)
        #pragma unroll
        for (int ni = 0; ni < FN; ++ni)
          acc[mi][ni] = __builtin_amdgcn_mfma_f32_16x16x32_bf16(
              af[mi], bfv[ni], acc[mi][ni], 0, 0, 0);
    }
  }
  // C/D layout: col = lane&15, row = quad*4 + reg  (m89/m91 verified)
  #pragma unroll
  for (int mi = 0; mi < FM; ++mi)
    #pragma unroll
    for (int ni = 0; ni < FN; ++ni) {
      const int rb = i0 + wm + mi * 16 + quad * 4;
      const int c  = j0 + wn + ni * 16 + m16;
      #pragma unroll
      for (int rg = 0; rg < 4; ++rg) epi(rb + rg, c, acc[mi][ni][rg]);
    }
}

// ---------------- epilogues ----------------
struct EpiSplit3Bias {          // x@[wg|w2|w1]: -> Wh_g | x_4att | xw(+bias)
  u16 *whg, *x4, *xw; const float* bias;
  DI void operator()(int r, int c, float v) const {
    if (c < 256)      whg[r * 256 + c] = to_bf(v);
    else if (c < 512) x4[r * 256 + (c - 256)] = to_bf(v);
    else              xw[r * 256 + (c - 512)] = to_bf(v + bias[c - 512]);
  }
};
struct EpiScaleSplit2 {         // expA@[H|Wh_g] * (1/rowsum) -> g2h bf16 | G1 f32
  const float* rsInv; u16* g2h; float* g1;
  DI void operator()(int r, int c, float v) const {
    float x = v * rsInv[r];
    if (c < 2048) g2h[(size_t)r * 2048 + c] = to_bf(x);
    else          g1[r * 256 + (c - 2048)] = x;
  }
};
struct EpiBf16 { u16* out; int ldn;
  DI void operator()(int r, int c, float v) const { out[(size_t)r * ldn + c] = to_bf(v); } };
struct EpiBf16Scale { u16* out; int ldn; float s;
  DI void operator()(int r, int c, float v) const { out[(size_t)r * ldn + c] = to_bf(v * s); } };
struct EpiSplit2 { u16 *o0, *o1;
  DI void operator()(int r, int c, float v) const {
    if (c < 256) o0[r * 256 + c] = to_bf(v); else o1[r * 256 + (c - 256)] = to_bf(v); } };
struct EpiF32 { float* out; int ldn;
  DI void operator()(int r, int c, float v) const { out[(size_t)r * ldn + c] = v; } };

// ---------------- small kernels ----------------
__global__ void k_diag(u32* abits) {                // A diagonal = 1
  int i = blockIdx.x * 256 + threadIdx.x;
  if (i < NN) abits[i * 128 + (i >> 5)] = 1u << (i & 31);
}

__global__ void k_scatter(const int* __restrict__ hidx, u32* hbits, u32* hbitsT,
                          u16* hbT) {               // incidence bitsets + H^T bf16
  int k = blockIdx.x * 256 + threadIdx.x;
  if (k >= NNZb) return;
  int n = hidx[k], e = hidx[NNZb + k];
  atomicOr(&hbits[n * 64 + (e >> 5)], 1u << (e & 31));
  atomicOr(&hbitsT[e * 128 + (n >> 5)], 1u << (n & 31));
  hbT[(size_t)e * NN + n] = 0x3F80;                 // bf16 1.0
}

__global__ void k_wcast(const float* wg, const float* w2, const float* w1,
                        const float* w3, u16* wcatT) {  // weights -> bf16, transposed
  int idx = blockIdx.x * 256 + threadIdx.x;         // 4*65536
  int blk = idx >> 16, r = idx & 65535;
  int d = r >> 8, k = r & 255;
  const float* src = blk == 0 ? wg : blk == 1 ? w2 : blk == 2 ? w1 : w3;
  wcatT[idx] = to_bf(src[k * 256 + d]);
}

__global__ void k_cast(const float* __restrict__ in, u16* __restrict__ out) {
  int idx = blockIdx.x * 256 + threadIdx.x;
  out[idx] = to_bf(in[idx]);
}

__global__ void k_rowdots(const u16* __restrict__ whg, const u16* __restrict__ x4,
                          const float* __restrict__ ag, const float* __restrict__ wc,
                          float* wh1, float* wh2, float* v) {
  int wv = threadIdx.x >> 6, l = threadIdx.x & 63;
  int row = blockIdx.x * 4 + wv;
  float s1 = 0, s2 = 0, s3 = 0;
  #pragma unroll
  for (int dd = 0; dd < 4; ++dd) {
    int d = l * 4 + dd;
    float a = from_bf(whg[row * 256 + d]);
    s1 += a * ag[d]; s2 += a * ag[256 + d];
    s3 += from_bf(x4[row * 256 + d]) * wc[d];
  }
  s1 = wredf(s1); s2 = wredf(s2); s3 = wredf(s3);
  if (l == 0) { wh1[row] = s1; wh2[row] = s2; v[row] = s3 * (1.0f / 16.0f); }
}

__global__ void k_clique(const u32* __restrict__ hbitsT, u32* abits) {
  int e = blockIdx.x, tid = threadIdx.x;
  __shared__ int list[512];
  __shared__ int cnt;
  if (tid == 0) cnt = 0;
  __syncthreads();
  if (tid < 128) {
    u32 w = hbitsT[e * 128 + tid];
    while (w) {
      int b = __ffs(w) - 1;
      int p = atomicAdd(&cnt, 1);
      if (p < 512) list[p] = tid * 32 + b;
      w &= w - 1;
    }
  }
  __syncthreads();
  int c = cnt < 512 ? cnt : 512;
  for (int p = tid; p < c * c; p += 256) {
    int i = list[p / c], j = list[p % c];
    atomicOr(&abits[i * 128 + (j >> 5)], 1u << (j & 31));
  }
}

__global__ void k_exprows(const u32* __restrict__ abits, const float* __restrict__ wh1,
                          const float* __restrict__ wh2, u16* __restrict__ expA,
                          float* rsInv) {           // masked exp(lrelu) rows + 1/rowsum
  int i = blockIdx.x, tid = threadIdx.x;
  __shared__ float w2s[NN];
  __shared__ float ssum;
  for (int j = tid; j < NN; j += 256) w2s[j] = wh2[j];
  if (tid == 0) ssum = 0.f;
  __syncthreads();
  float a = wh1[i], lsum = 0.f;
  for (int j = tid; j < NN; j += 256) {
    u32 w = abits[i * 128 + (j >> 5)];
    u16 h = 0;
    if ((w >> (j & 31)) & 1) {
      float z = a + w2s[j];
      float eg = z > 0.f ? z : 0.2f * z;            // LeakyReLU(0.2)
      h = to_bf(__expf(eg));
      lsum += from_bf(h);                           // sum the rounded values
    }
    expA[(size_t)i * NN + j] = h;
  }
  lsum = wredf(lsum);
  if ((tid & 63) == 0) atomicAdd(&ssum, lsum);
  __syncthreads();
  if (tid == 0) rsInv[i] = 1.0f / ssum;
}

__global__ void k_edge_softmax(const u16* __restrict__ g2hT, const u32* __restrict__ hbitsT,
                               const float* __restrict__ v, u16* __restrict__ att1) {
  int e = blockIdx.x, tid = threadIdx.x;
  __shared__ float evals[NN];
  __shared__ u32 hw[128];
  __shared__ float s1s, s2s; __shared__ int cs;
  if (tid == 0) { s1s = 0.f; s2s = 0.f; cs = 0; }
  if (tid < 128) hw[tid] = hbitsT[e * 128 + tid];
  __syncthreads();
  float sum1 = 0.f;
  for (int j = tid; j < NN; j += 256) {
    float ev = __expf(from_bf(g2hT[(size_t)e * NN + j]));
    evals[j] = ev; sum1 += ev;
  }
  float sum2 = 0.f; int cnt = 0;
  if (tid < 128) {
    u32 w = hw[tid]; cnt = __popc(w);
    while (w) { int b = __ffs(w) - 1; sum2 += __expf(v[tid * 32 + b]); w &= w - 1; }
  }
  sum1 = wredf(sum1); sum2 = wredf(sum2); cnt = wredi(cnt);
  if ((tid & 63) == 0) { atomicAdd(&s1s, sum1); atomicAdd(&s2s, sum2); atomicAdd(&cs, cnt); }
  __syncthreads();
  float inv1 = 1.0f / s1s;
  int c = cs;
  float inv2 = c > 0 ? 1.0f / s2s : 0.0f;
  float unif = c > 0 ? 0.0f : (1.0f / (float)NN);   // empty-edge fallback
  for (int j = tid; j < NN; j += 256) {
    float t = evals[j] * inv1 + unif;
    if ((hw[j >> 5] >> (j & 31)) & 1) t += __expf(v[j]) * inv2;
    att1[(size_t)e * NN + j] = to_bf(t);
  }
}

__global__ void k_node_softmax(const u16* __restrict__ g2h, const u16* __restrict__ attn2,
                               const u32* __restrict__ hbits, u16* __restrict__ att2hn) {
  int n = blockIdx.x, tid = threadIdx.x;
  __shared__ float ev3[EE], ev4[EE];
  __shared__ u32 hw[64];
  __shared__ float s3s, s4s; __shared__ int cs;
  if (tid == 0) { s3s = 0.f; s4s = 0.f; cs = 0; }
  if (tid < 64) hw[tid] = hbits[n * 64 + tid];
  __syncthreads();
  float s3 = 0.f, s4 = 0.f; int cl = 0;
  for (int e = tid; e < EE; e += 256) {
    float x3 = __expf(from_bf(g2h[(size_t)n * EE + e]));
    ev3[e] = x3; s3 += x3;
    bool m = (hw[e >> 5] >> (e & 31)) & 1;
    float x4 = m ? __expf(from_bf(attn2[(size_t)n * EE + e])) : 0.f;
    ev4[e] = x4; s4 += x4; cl += m;
  }
  s3 = wredf(s3); s4 = wredf(s4); cl = wredi(cl);
  if ((tid & 63) == 0) { atomicAdd(&s3s, s3); atomicAdd(&s4s, s4); atomicAdd(&cs, cl); }
  __syncthreads();
  float inv3 = 1.0f / s3s;
  int c = cs;
  float inv4 = c > 0 ? 1.0f / s4s : 0.0f;
  float unif = c > 0 ? 0.0f : (1.0f / (float)EE);   // isolated-node fallback
  for (int e = tid; e < EE; e += 256)
    att2hn[(size_t)n * EE + e] = to_bf(ev3[e] * inv3 + ev4[e] * inv4 + unif);
}

__global__ void k_transpose(const u16* __restrict__ in, u16* __restrict__ out,
                            int R, int C) {         // out[C,R] = in[R,C]^T
  __shared__ u16 t[32][33];
  int x0 = blockIdx.x * 32, y0 = blockIdx.y * 32;
  int tx = threadIdx.x, ty = threadIdx.y;
  #pragma unroll
  for (int k = 0; k < 32; k += 8)
    t[ty + k][tx] = in[(size_t)(y0 + ty + k) * C + x0 + tx];
  __syncthreads();
  #pragma unroll
  for (int k = 0; k < 32; k += 8)
    out[(size_t)(x0 + ty + k) * R + y0 + tx] = t[tx][ty + k];
}

__global__ void k_combine(const float* __restrict__ C1, const float* __restrict__ C2,
                          const float* __restrict__ G1, float* __restrict__ out) {
  int idx = blockIdx.x * 256 + threadIdx.x;         // 4096*256
  int r = idx >> 8, d = idx & 255;
  float nodev = C1[r * 512 + d];
  out[idx] = nodev > 0.f ? nodev : 0.f;             // ReLU
  float s = G1[idx] + C1[r * 512 + 256 + d] + C2[idx];
  out[1048576 + idx] = s > 0.f ? s : expm1f(s);     // ELU
}

// ---------------- launch ----------------
extern "C" void kernel_launch(void* const* d_in, const int* in_sizes, int n_in,
                              void* d_out, int out_size, void* d_ws, size_t ws_size,
                              hipStream_t stream) {
  (void)in_sizes; (void)n_in; (void)out_size; (void)ws_size;
  const float* x    = (const float*)d_in[0];
  const float* w1   = (const float*)d_in[1];   // weight
  const float* w2   = (const float*)d_in[2];   // weight2
  const float* w3   = (const float*)d_in[3];   // weight3
  const float* wg   = (const float*)d_in[4];   // weight_g
  const float* ag   = (const float*)d_in[5];   // a_g [512]
  const float* wc   = (const float*)d_in[6];   // word_context [256]
  const float* bias = (const float*)d_in[7];
  const int*   hidx = (const int*)d_in[8];     // [2,65536]
  float* out = (float*)d_out;
  char* ws = (char*)d_ws;

  u32* Hbits   = (u32*)(ws + OFF_HBITS);
  u32* HbitsT  = (u32*)(ws + OFF_HBITST);
  u32* Abits   = (u32*)(ws + OFF_ABITS);
  float* Wh1   = (float*)(ws + OFF_WH1);
  float* Wh2   = (float*)(ws + OFF_WH2);
  float* V     = (float*)(ws + OFF_V);
  float* RsInv = (float*)(ws + OFF_RSINV);
  u16* WcatT   = (u16*)(ws + OFF_WCATT);
  u16* W3T     = WcatT + 768 * 256;
  u16* Xb      = (u16*)(ws + OFF_XB);
  u16* Whg     = (u16*)(ws + OFF_WHG);
  u16* X4att   = (u16*)(ws + OFF_X4ATT);
  u16* Xw      = (u16*)(ws + OFF_XW);
  u16* XwT     = (u16*)(ws + OFF_XWT);
  u16* WhgT1   = (u16*)(ws + OFF_WHGT1);
  u16* HbT     = (u16*)(ws + OFF_HBT);
  u16* WhgT2   = (u16*)(ws + OFF_WHGT2);
  u16* ExpA    = (u16*)(ws + OFF_EXPA);
  u16* Att1    = (u16*)(ws + OFF_ATT1);
  u16* Att1T   = (u16*)(ws + OFF_ATT1T);
  u16* Att2hn  = (u16*)(ws + OFF_ATT2HN);
  u16* G2h     = (u16*)(ws + OFF_G2H);
  u16* G2hT    = (u16*)(ws + OFF_G2HT);
  u16* Att2hnT = (u16*)(ws + OFF_ATT2HNT);
  u16* Attn2   = (u16*)(ws + OFF_ATTN2);
  float* C1    = (float*)(ws + OFF_C1);
  float* C2    = (float*)(ws + OFF_C2);
  float* G1    = (float*)(ws + OFF_G1);
  u16* Edge    = (u16*)(ws + OFF_EDGE);
  u16* Edge2   = (u16*)(ws + OFF_EDGE2);
  u16* E4att   = (u16*)(ws + OFF_E4ATT);
  u16* Hn2     = (u16*)(ws + OFF_HN2);
  u16* EdgeT   = (u16*)(ws + OFF_EDGET);
  u16* Hn2T    = (u16*)(ws + OFF_HN2T);
  u16* Edge2T  = (u16*)(ws + OFF_EDGE2T);

  dim3 tb(32, 8);

  // --- setup: bitsets, H^T, weight/x casts ---
  hipMemsetAsync(ws + OFF_HBITS, 0, 4 * MB, stream);        // Hbits|HbitsT|Abits
  hipMemsetAsync(ws + OFF_HBT, 0, 16 * MB, stream);         // H^T bf16
  k_diag<<<16, 256, 0, stream>>>(Abits);
  k_scatter<<<256, 256, 0, stream>>>(hidx, Hbits, HbitsT, HbT);
  k_wcast<<<1024, 256, 0, stream>>>(wg, w2, w1, w3, WcatT);
  k_cast<<<4096, 256, 0, stream>>>(x, Xb);

  // --- Wh_g | x_4att | xw = x @ [wg|w2|w1] (+bias) ---
  gemm_nt<128, 128, EpiSplit3Bias><<<32 * 6, 256, 0, stream>>>(
      Xb, WcatT, 768, 256, EpiSplit3Bias{Whg, X4att, Xw, bias});
  k_rowdots<<<1024, 256, 0, stream>>>(Whg, X4att, ag, wc, Wh1, Wh2, V);
  k_transpose<<<dim3(8, 128), tb, 0, stream>>>(Whg, WhgT1, NN, DD);
  k_transpose<<<dim3(8, 128), tb, 0, stream>>>(Whg, WhgT2, NN, DD);
  k_transpose<<<dim3(8, 128), tb, 0, stream>>>(Xw, XwT, NN, DD);

  // --- A = (H@H^T>0) via cliques; expA rows + 1/rowsum ---
  k_clique<<<EE, 256, 0, stream>>>(HbitsT, Abits);
  k_exprows<<<NN, 256, 0, stream>>>(Abits, Wh1, Wh2, ExpA, RsInv);

  // --- big fused GEMM: attention_g @ [H | Wh_g] -> graph2hyper, G1 ---
  gemm_nt<128, 128, EpiScaleSplit2><<<32 * 18, 256, 0, stream>>>(
      ExpA, HbT, 2304, NN, EpiScaleSplit2{RsInv, G2h, G1});
  k_transpose<<<dim3(64, 128), tb, 0, stream>>>(G2h, G2hT, NN, EE);

  // --- att1 = softmax(g2h^T) + masked softmax(v) per edge ---
  k_edge_softmax<<<EE, 256, 0, stream>>>(G2hT, HbitsT, V, Att1);
  k_transpose<<<dim3(128, 64), tb, 0, stream>>>(Att1, Att1T, EE, NN);

  // --- edge | edge2 = att1 @ [xw | Wh_g] ---
  gemm_nt<64, 64, EpiSplit2><<<32 * 8, 256, 0, stream>>>(
      Att1, XwT, 512, NN, EpiSplit2{Edge, Edge2});
  // --- edge_4att = edge @ w3 ---
  gemm_nt<64, 64, EpiBf16><<<32 * 4, 256, 0, stream>>>(
      Edge, W3T, 256, 256, EpiBf16{E4att, 256});
  // --- attn2 = (x_4att @ edge_4att^T)/temp ---
  gemm_nt<128, 128, EpiBf16Scale><<<32 * 16, 256, 0, stream>>>(
      X4att, E4att, EE, 256, EpiBf16Scale{Attn2, EE, 1.0f / 16.0f});

  // --- att2hn = softmax(g2h) + masked softmax(attn2) per node ---
  k_node_softmax<<<NN, 256, 0, stream>>>(G2h, Attn2, Hbits, Att2hn);
  k_transpose<<<dim3(64, 128), tb, 0, stream>>>(Att2hn, Att2hnT, NN, EE);

  // --- hn2 = att2hn^T @ Wh_g ---
  gemm_nt<64, 64, EpiBf16><<<32 * 4, 256, 0, stream>>>(
      Att2hnT, WhgT1, 256, NN, EpiBf16{Hn2, 256});

  k_transpose<<<dim3(8, 64), tb, 0, stream>>>(Edge, EdgeT, EE, DD);
  k_transpose<<<dim3(8, 64), tb, 0, stream>>>(Hn2, Hn2T, EE, DD);
  k_transpose<<<dim3(8, 64), tb, 0, stream>>>(Edge2, Edge2T, EE, DD);

  // --- C1 = att2hn @ [edge | hn2] ; C2 = att1^T @ edge2 ---
  gemm_nt<64, 64, EpiF32><<<64 * 8, 256, 0, stream>>>(
      Att2hn, EdgeT, 512, EE, EpiF32{C1, 512});
  gemm_nt<64, 64, EpiF32><<<64 * 4, 256, 0, stream>>>(
      Att1T, Edge2T, 256, EE, EpiF32{C2, 256});

  // --- node = relu(C1[:, :256]); h_prime = elu(G1 + C1[:,256:] + C2) ---
  k_combine<<<4096, 256, 0, stream>>>(C1, C2, G1, out);
}

// Round 2
// 445.711 us; speedup vs baseline: 1.0877x; 1.0877x over previous
//
#include <hip/hip_runtime.h>
#include <cstdint>
#include <cstddef>

// ============================================================================
// ProposedConv hypergraph dual-attention, restructured (round 2):
//  - epilogue f32x4 interface: GEMMs write normal + transposed outputs
//    directly (8B stores on the T side) -> G2hT / XwT / WhgT transposes gone
//  - split-K f32-atomicAdd GEMMs for the thin long-K products (edge, hn2,
//    C1, C2): 1024-block grids instead of 128-512 latency-bound blocks
//  - attn2 re-associated: Y = x@(w3@w2^T)^T folded into G0; e4att GEMM gone
// ============================================================================

#define DI __device__ __forceinline__
typedef unsigned short u16;
typedef unsigned int   u32;
typedef __bf16 bf16x8 __attribute__((ext_vector_type(8)));
typedef float  f32x4  __attribute__((ext_vector_type(4)));

constexpr int NN  = 4096;   // nodes
constexpr int EE  = 2048;   // hyperedges
constexpr int NNZb = 65536; // incidence nnz

// ---------------- workspace layout (bytes), peak 126 MB ----------------
constexpr size_t MB = (size_t)1 << 20;
constexpr size_t OFF_HBITS   = 0;          // u32 [4096][64]   (1 MB)
constexpr size_t OFF_HBITST  = 1*MB;       // u32 [2048][128]  (1 MB)
constexpr size_t OFF_ABITS   = 2*MB;       // u32 [4096][128]  (2 MB); Edge bf16 reuses [2,3) after
constexpr size_t OFF_EDGE    = 2*MB;       //   bf16 [2048][256] (Abits dead after k_exprows)
constexpr size_t OFF_WH1     = 4*MB;
constexpr size_t OFF_WH2     = 4*MB + 16384;
constexpr size_t OFF_V       = 4*MB + 32768;
constexpr size_t OFF_RSINV   = 4*MB + 49152;
constexpr size_t OFF_WCAT    = 5*MB;       // bf16: [wgT|w2T|w1T|W23'] (1024x256) + w3b + w2b
constexpr size_t OFF_XB      = 6*MB;       // bf16 [4096][256]; then EdgeT [6,7), Hn2T [7,8)
constexpr size_t OFF_EDGET   = 6*MB;       //   bf16 [256][2048]
constexpr size_t OFF_HN2T    = 7*MB;       //   bf16 [256][2048]  ([EdgeT|Hn2T] = C1's B-cat)
constexpr size_t OFF_WHG     = 8*MB;       // bf16 [4096][256]
constexpr size_t OFF_X4ATT   = 10*MB;      // bf16 [4096][256]
constexpr size_t OFF_YB      = 12*MB;      // bf16 [4096][256]  Y = x @ W23'^T
constexpr size_t OFF_XWT     = 14*MB;      // bf16 [256][4096]  ([XwT|WhgTa] = edge's B-cat)
constexpr size_t OFF_WHGTA   = 16*MB;      // bf16 [256][4096]
constexpr size_t OFF_HBT     = 18*MB;      // bf16 [2048][4096]; Edge2T reuses [18,19) after big GEMM
constexpr size_t OFF_EDGE2T  = 18*MB;      //   bf16 [256][2048]
constexpr size_t OFF_WHGTB   = 34*MB;      // bf16 [256][4096]  ([HbT|WhgTb] = big GEMM's B-cat)
constexpr size_t OFF_EXPA    = 36*MB;      // bf16 [4096][4096]; dead after big GEMM
constexpr size_t OFF_ATT1    = 36*MB;      //   bf16 [2048][4096]; dead after edge GEMM
constexpr size_t OFF_ATT2HN  = 36*MB;      //   bf16 [4096][2048]
constexpr size_t OFF_ATT1T   = 52*MB;      // bf16 [4096][2048]
constexpr size_t OFF_G2H     = 68*MB;      // bf16 [4096][2048]
constexpr size_t OFF_G2HT    = 84*MB;      // bf16 [2048][4096]; dead after edge_softmax
constexpr size_t OFF_ATT2HNT = 84*MB;      //   bf16 [2048][4096]
constexpr size_t OFF_ATTN2   = 100*MB;     // bf16 [4096][2048]; dead after node_softmax
constexpr size_t OFF_C1      = 100*MB;     //   f32 [4096][512] (atomic, memset mid-graph)
constexpr size_t OFF_C2      = 108*MB;     //   f32 [4096][256]
constexpr size_t OFF_G1      = 116*MB;     // f32 [4096][256]
constexpr size_t OFF_EDGEACC = 120*MB;     // f32 [2048][512] (atomic)
constexpr size_t OFF_HN2ACC  = 124*MB;     // f32 [2048][256] (atomic)

// ---------------- helpers ----------------
DI u16 to_bf(float f) {
  union { float f; u32 u; } x; x.f = f;
  u32 r = x.u + 0x7fffu + ((x.u >> 16) & 1u);
  return (u16)(r >> 16);
}
DI float from_bf(u16 h) { union { u32 u; float f; } x; x.u = (u32)h << 16; return x.f; }
DI void store_bf4(u16* p, float a, float b, float c, float d) {  // 8B aligned store
  u32 lo = (u32)to_bf(a) | ((u32)to_bf(b) << 16);
  u32 hi = (u32)to_bf(c) | ((u32)to_bf(d) << 16);
  *(u32*)p = lo; *((u32*)p + 1) = hi;
}

DI float wredf(float v) {
  #pragma unroll
  for (int o = 32; o; o >>= 1) v += __shfl_down(v, o);
  return v;
}
DI int wredi(int v) {
  #pragma unroll
  for (int o = 32; o; o >>= 1) v += __shfl_down(v, o);
  return v;
}

typedef __attribute__((address_space(3))) void lds_void;
typedef __attribute__((address_space(1))) void glb_void;
DI void async_load16(const void* g, void* l) {
  __builtin_amdgcn_global_load_lds((glb_void*)(uintptr_t)g,
                                   (lds_void*)(u32)(uintptr_t)l, 16, 0, 0);
}

// ---------------- generic NT bf16 GEMM with split-K ----------------
// C[m][n] = sum_k A[m][k]*B[n][k]; A:[M,K] B:[N,K] row-major bf16.
// Grid = (M/BM)*(N/BN)*S blocks; split s handles K-range [s*K/S,(s+1)*K/S).
// Epi is called as epi(rb, c, f32x4) covering rows rb..rb+3, column c.
template <int BM, int BN, int S, class Epi>
__global__ __launch_bounds__(256, 2)
void gemm_nt(const u16* __restrict__ A, const u16* __restrict__ B,
             int N, int K, Epi epi)
{
  constexpr int BK = 64;
  constexpr int WM = BM / 2, WN = BN / 2;
  constexpr int FM = WM / 16, FN = WN / 16;
  constexpr int AI = (BM * 8) / 256, BI = (BN * 8) / 256;
  __shared__ __align__(16) u16 As[BM * BK];
  __shared__ __align__(16) u16 Bs[BN * BK];

  const int tid = threadIdx.x;
  const int w = tid >> 6, l = tid & 63;
  const int nb = N / BN;
  const int tilesPer = gridDim.x / S;
  int t = blockIdx.x;
  const int s = t / tilesPer; t -= s * tilesPer;
  const int bi = t / nb, bj = t - bi * nb;
  const int i0 = bi * BM, j0 = bj * BN;
  const int kLen = K / S, k0 = s * kLen;
  const int wm = (w & 1) * WM, wn = (w >> 1) * WN;
  const int quad = l >> 4, m16 = l & 15;

  f32x4 acc[FM][FN] = {};

  for (int kb = k0; kb < k0 + kLen; kb += BK) {
    __syncthreads();
    #pragma unroll
    for (int i = 0; i < AI; ++i) {
      const int ci = (i * 4 + w) * 64 + l;
      const int r = ci >> 3;
      const int lc = (ci & 7) ^ (r & 7);
      async_load16(A + (size_t)(i0 + r) * K + kb + lc * 8, &As[(i * 4 + w) * 512]);
    }
    #pragma unroll
    for (int i = 0; i < BI; ++i) {
      const int ci = (i * 4 + w) * 64 + l;
      const int r = ci >> 3;
      const int lc = (ci & 7) ^ (r & 7);
      async_load16(B + (size_t)(j0 + r) * K + kb + lc * 8, &Bs[(i * 4 + w) * 512]);
    }
    __syncthreads();
    #pragma unroll
    for (int ks = 0; ks < 2; ++ks) {
      bf16x8 af[FM], bfv[FN];
      #pragma unroll
      for (int mi = 0; mi < FM; ++mi) {
        const int row = wm + mi * 16 + m16;
        af[mi] = *(const bf16x8*)&As[row * BK + (((ks * 4 + quad) ^ (row & 7)) * 8)];
      }
      #pragma unroll
      for (int ni = 0; ni < FN; ++ni) {
        const int row = wn + ni * 16 + m16;
        bfv[ni] = *(const bf16x8*)&Bs[row * BK + (((ks * 4 + quad) ^ (row & 7)) * 8)];
      }
      #pragma unroll
      for (int mi = 0; mi < FM; ++mi)
        #pragma unroll
        for (int ni = 0; ni < FN; ++ni)
          acc[mi][ni] = __builtin_amdgcn_mfma_f32_16x16x32_bf16(
              af[mi], bfv[ni], acc[mi][ni], 0, 0, 0);
    }
  }
  // C/D layout: col = lane&15, row = quad*4 + reg
  #pragma unroll
  for (int mi = 0; mi < FM; ++mi)
    #pragma unroll
    for (int ni = 0; ni < FN; ++ni) {
      const int rb = i0 + wm + mi * 16 + quad * 4;
      const int c  = j0 + wn + ni * 16 + m16;
      epi(rb, c, acc[mi][ni]);
    }
}

// ---------------- epilogues (rb..rb+3 rows, col c) ----------------
struct EpiG0 {   // x @ [wgT|w2T|w1T|W23']: Whg(+2 transposed) | X4att | XwT(+bias) | Yb
  u16 *whg, *whgTa, *whgTb, *x4, *xwT, *yb; const float* bias;
  DI void operator()(int r, int c, f32x4 v) const {
    if (c < 256) {
      #pragma unroll
      for (int i = 0; i < 4; ++i) whg[(r + i) * 256 + c] = to_bf(v[i]);
      store_bf4(&whgTa[(size_t)c * NN + r], v[0], v[1], v[2], v[3]);
      store_bf4(&whgTb[(size_t)c * NN + r], v[0], v[1], v[2], v[3]);
    } else if (c < 512) {
      #pragma unroll
      for (int i = 0; i < 4; ++i) x4[(r + i) * 256 + (c - 256)] = to_bf(v[i]);
    } else if (c < 768) {
      float b = bias[c - 512];
      store_bf4(&xwT[(size_t)(c - 512) * NN + r], v[0]+b, v[1]+b, v[2]+b, v[3]+b);
    } else {
      #pragma unroll
      for (int i = 0; i < 4; ++i) yb[(r + i) * 256 + (c - 768)] = to_bf(v[i]);
    }
  }
};
struct EpiBig {  // expA @ [H|Whg] * (1/rowsum) -> G2h + G2hT + G1
  const float* rsInv; u16* g2h; u16* g2hT; float* g1;
  DI void operator()(int r, int c, f32x4 v) const {
    float w0 = v[0]*rsInv[r], w1 = v[1]*rsInv[r+1], w2 = v[2]*rsInv[r+2], w3 = v[3]*rsInv[r+3];
    if (c < 2048) {
      g2h[(size_t)r * EE + c] = to_bf(w0);
      g2h[(size_t)(r+1) * EE + c] = to_bf(w1);
      g2h[(size_t)(r+2) * EE + c] = to_bf(w2);
      g2h[(size_t)(r+3) * EE + c] = to_bf(w3);
      store_bf4(&g2hT[(size_t)c * NN + r], w0, w1, w2, w3);
    } else {
      g1[(r) * 256 + (c - 2048)] = w0;
      g1[(r+1) * 256 + (c - 2048)] = w1;
      g1[(r+2) * 256 + (c - 2048)] = w2;
      g1[(r+3) * 256 + (c - 2048)] = w3;
    }
  }
};
struct EpiAtomF32 { float* out; int ldn;
  DI void operator()(int r, int c, f32x4 v) const {
    #pragma unroll
    for (int i = 0; i < 4; ++i) atomicAdd(&out[(size_t)(r + i) * ldn + c], v[i]);
  } };
struct EpiBf16 { u16* out; int ldn;
  DI void operator()(int r, int c, f32x4 v) const {
    #pragma unroll
    for (int i = 0; i < 4; ++i) out[(size_t)(r + i) * ldn + c] = to_bf(v[i]);
  } };
struct EpiBf16Scale { u16* out; int ldn; float s;
  DI void operator()(int r, int c, f32x4 v) const {
    #pragma unroll
    for (int i = 0; i < 4; ++i) out[(size_t)(r + i) * ldn + c] = to_bf(v[i] * s);
  } };

// ---------------- small kernels ----------------
__global__ void k_diag(u32* abits) {
  int i = blockIdx.x * 256 + threadIdx.x;
  if (i < NN) abits[i * 128 + (i >> 5)] = 1u << (i & 31);
}

__global__ void k_scatter(const int* __restrict__ hidx, u32* hbits, u32* hbitsT,
                          u16* hbT) {
  int k = blockIdx.x * 256 + threadIdx.x;
  if (k >= NNZb) return;
  int n = hidx[k], e = hidx[NNZb + k];
  atomicOr(&hbits[n * 64 + (e >> 5)], 1u << (e & 31));
  atomicOr(&hbitsT[e * 128 + (n >> 5)], 1u << (n & 31));
  hbT[(size_t)e * NN + n] = 0x3F80;            // bf16 1.0
}

__global__ void k_wcast(const float* wg, const float* w2, const float* w1,
                        const float* w3, u16* wcat) {
  int idx = blockIdx.x * 256 + threadIdx.x;    // 5*65536
  int blk = idx >> 16, r = idx & 65535;
  if (blk < 3) {
    int d = r >> 8, k = r & 255;
    const float* src = blk == 0 ? wg : blk == 1 ? w2 : w1;
    wcat[idx] = to_bf(src[k * 256 + d]);       // transposed
  } else if (blk == 3) {
    wcat[4 * 65536 + r] = to_bf(w3[r]);        // w3b straight
  } else {
    wcat[5 * 65536 + r] = to_bf(w2[r]);        // w2b straight
  }
}

__global__ void k_cast(const float* __restrict__ in, u16* __restrict__ out) {
  int idx = blockIdx.x * 256 + threadIdx.x;
  out[idx] = to_bf(in[idx]);
}

__global__ void k_rowdots(const u16* __restrict__ whg, const u16* __restrict__ x4,
                          const float* __restrict__ ag, const float* __restrict__ wc,
                          float* wh1, float* wh2, float* v) {
  int wv = threadIdx.x >> 6, l = threadIdx.x & 63;
  int row = blockIdx.x * 4 + wv;
  float s1 = 0, s2 = 0, s3 = 0;
  #pragma unroll
  for (int dd = 0; dd < 4; ++dd) {
    int d = l * 4 + dd;
    float a = from_bf(whg[row * 256 + d]);
    s1 += a * ag[d]; s2 += a * ag[256 + d];
    s3 += from_bf(x4[row * 256 + d]) * wc[d];
  }
  s1 = wredf(s1); s2 = wredf(s2); s3 = wredf(s3);
  if (l == 0) { wh1[row] = s1; wh2[row] = s2; v[row] = s3 * (1.0f / 16.0f); }
}

__global__ void k_clique(const u32* __restrict__ hbitsT, u32* abits) {
  int e = blockIdx.x, tid = threadIdx.x;
  __shared__ int list[512];
  __shared__ int cnt;
  if (tid == 0) cnt = 0;
  __syncthreads();
  if (tid < 128) {
    u32 w = hbitsT[e * 128 + tid];
    while (w) {
      int b = __ffs(w) - 1;
      int p = atomicAdd(&cnt, 1);
      if (p < 512) list[p] = tid * 32 + b;
      w &= w - 1;
    }
  }
  __syncthreads();
  int c = cnt < 512 ? cnt : 512;
  for (int p = tid; p < c * c; p += 256) {
    int i = list[p / c], j = list[p % c];
    atomicOr(&abits[i * 128 + (j >> 5)], 1u << (j & 31));
  }
}

__global__ void k_exprows(const u32* __restrict__ abits, const float* __restrict__ wh1,
                          const float* __restrict__ wh2, u16* __restrict__ expA,
                          float* rsInv) {
  int i = blockIdx.x, tid = threadIdx.x;
  __shared__ float w2s[NN];
  __shared__ float ssum;
  for (int j = tid; j < NN; j += 256) w2s[j] = wh2[j];
  if (tid == 0) ssum = 0.f;
  __syncthreads();
  float a = wh1[i], lsum = 0.f;
  for (int j = tid; j < NN; j += 256) {
    u32 w = abits[i * 128 + (j >> 5)];
    u16 h = 0;
    if ((w >> (j & 31)) & 1) {
      float z = a + w2s[j];
      float eg = z > 0.f ? z : 0.2f * z;
      h = to_bf(__expf(eg));
      lsum += from_bf(h);
    }
    expA[(size_t)i * NN + j] = h;
  }
  lsum = wredf(lsum);
  if ((tid & 63) == 0) atomicAdd(&ssum, lsum);
  __syncthreads();
  if (tid == 0) rsInv[i] = 1.0f / ssum;
}

__global__ void k_edge_softmax(const u16* __restrict__ g2hT, const u32* __restrict__ hbitsT,
                               const float* __restrict__ v, u16* __restrict__ att1) {
  int e = blockIdx.x, tid = threadIdx.x;
  __shared__ float evals[NN];
  __shared__ u32 hw[128];
  __shared__ float s1s, s2s; __shared__ int cs;
  if (tid == 0) { s1s = 0.f; s2s = 0.f; cs = 0; }
  if (tid < 128) hw[tid] = hbitsT[e * 128 + tid];
  __syncthreads();
  float sum1 = 0.f;
  for (int j = tid; j < NN; j += 256) {
    float ev = __expf(from_bf(g2hT[(size_t)e * NN + j]));
    evals[j] = ev; sum1 += ev;
  }
  float sum2 = 0.f; int cnt = 0;
  if (tid < 128) {
    u32 w = hw[tid]; cnt = __popc(w);
    while (w) { int b = __ffs(w) - 1; sum2 += __expf(v[tid * 32 + b]); w &= w - 1; }
  }
  sum1 = wredf(sum1); sum2 = wredf(sum2); cnt = wredi(cnt);
  if ((tid & 63) == 0) { atomicAdd(&s1s, sum1); atomicAdd(&s2s, sum2); atomicAdd(&cs, cnt); }
  __syncthreads();
  float inv1 = 1.0f / s1s;
  int c = cs;
  float inv2 = c > 0 ? 1.0f / s2s : 0.0f;
  float unif = c > 0 ? 0.0f : (1.0f / (float)NN);
  for (int j = tid; j < NN; j += 256) {
    float t = evals[j] * inv1 + unif;
    if ((hw[j >> 5] >> (j & 31)) & 1) t += __expf(v[j]) * inv2;
    att1[(size_t)e * NN + j] = to_bf(t);
  }
}

__global__ void k_node_softmax(const u16* __restrict__ g2h, const u16* __restrict__ attn2,
                               const u32* __restrict__ hbits, u16* __restrict__ att2hn) {
  int n = blockIdx.x, tid = threadIdx.x;
  __shared__ float ev3[EE], ev4[EE];
  __shared__ u32 hw[64];
  __shared__ float s3s, s4s; __shared__ int cs;
  if (tid == 0) { s3s = 0.f; s4s = 0.f; cs = 0; }
  if (tid < 64) hw[tid] = hbits[n * 64 + tid];
  __syncthreads();
  float s3 = 0.f, s4 = 0.f; int cl = 0;
  for (int e = tid; e < EE; e += 256) {
    float x3 = __expf(from_bf(g2h[(size_t)n * EE + e]));
    ev3[e] = x3; s3 += x3;
    bool m = (hw[e >> 5] >> (e & 31)) & 1;
    float x4 = m ? __expf(from_bf(attn2[(size_t)n * EE + e])) : 0.f;
    ev4[e] = x4; s4 += x4; cl += m;
  }
  s3 = wredf(s3); s4 = wredf(s4); cl = wredi(cl);
  if ((tid & 63) == 0) { atomicAdd(&s3s, s3); atomicAdd(&s4s, s4); atomicAdd(&cs, cl); }
  __syncthreads();
  float inv3 = 1.0f / s3s;
  int c = cs;
  float inv4 = c > 0 ? 1.0f / s4s : 0.0f;
  float unif = c > 0 ? 0.0f : (1.0f / (float)EE);
  for (int e = tid; e < EE; e += 256)
    att2hn[(size_t)n * EE + e] = to_bf(ev3[e] * inv3 + ev4[e] * inv4 + unif);
}

__global__ void k_transpose(const u16* __restrict__ in, u16* __restrict__ out,
                            int R, int C) {     // out[C,R] = in[R,C]^T
  __shared__ u16 t[32][33];
  int x0 = blockIdx.x * 32, y0 = blockIdx.y * 32;
  int tx = threadIdx.x, ty = threadIdx.y;
  #pragma unroll
  for (int k = 0; k < 32; k += 8)
    t[ty + k][tx] = in[(size_t)(y0 + ty + k) * C + x0 + tx];
  __syncthreads();
  #pragma unroll
  for (int k = 0; k < 32; k += 8)
    out[(size_t)(x0 + ty + k) * R + y0 + tx] = t[tx][ty + k];
}

// EdgeAcc f32 [2048,512] -> Edge bf16 (cols<256), EdgeT, Edge2T (transposed)
__global__ void k_cast_edge(const float* __restrict__ acc, u16* edge,
                            u16* edgeT, u16* edge2T) {
  __shared__ float t[32][33];
  int c0 = blockIdx.x * 32, r0 = blockIdx.y * 32;
  int tx = threadIdx.x, ty = threadIdx.y;
  #pragma unroll
  for (int k = 0; k < 32; k += 8) {
    float v = acc[(size_t)(r0 + ty + k) * 512 + c0 + tx];
    t[ty + k][tx] = v;
    if (c0 < 256) edge[(r0 + ty + k) * 256 + c0 + tx] = to_bf(v);
  }
  __syncthreads();
  u16* dst = c0 < 256 ? edgeT : edge2T;
  int cc0 = c0 & 255;
  #pragma unroll
  for (int k = 0; k < 32; k += 8)
    dst[(size_t)(cc0 + ty + k) * EE + r0 + tx] = to_bf(t[tx][ty + k]);
}

// Hn2Acc f32 [2048,256] -> Hn2T bf16 [256,2048]
__global__ void k_cast_hn2(const float* __restrict__ acc, u16* hn2T) {
  __shared__ float t[32][33];
  int c0 = blockIdx.x * 32, r0 = blockIdx.y * 32;
  int tx = threadIdx.x, ty = threadIdx.y;
  #pragma unroll
  for (int k = 0; k < 32; k += 8)
    t[ty + k][tx] = acc[(size_t)(r0 + ty + k) * 256 + c0 + tx];
  __syncthreads();
  #pragma unroll
  for (int k = 0; k < 32; k += 8)
    hn2T[(size_t)(c0 + ty + k) * EE + r0 + tx] = to_bf(t[tx][ty + k]);
}

__global__ void k_combine(const float* __restrict__ C1, const float* __restrict__ C2,
                          const float* __restrict__ G1, float* __restrict__ out) {
  int idx = blockIdx.x * 256 + threadIdx.x;     // 4096*256
  int r = idx >> 8, d = idx & 255;
  float nodev = C1[r * 512 + d];
  out[idx] = nodev > 0.f ? nodev : 0.f;                       // ReLU
  float s = G1[idx] + C1[r * 512 + 256 + d] + C2[idx];
  out[1048576 + idx] = s > 0.f ? s : expm1f(s);               // ELU
}

// ---------------- launch ----------------
extern "C" void kernel_launch(void* const* d_in, const int* in_sizes, int n_in,
                              void* d_out, int out_size, void* d_ws, size_t ws_size,
                              hipStream_t stream) {
  (void)in_sizes; (void)n_in; (void)out_size; (void)ws_size;
  const float* x    = (const float*)d_in[0];
  const float* w1   = (const float*)d_in[1];
  const float* w2   = (const float*)d_in[2];
  const float* w3   = (const float*)d_in[3];
  const float* wg   = (const float*)d_in[4];
  const float* ag   = (const float*)d_in[5];
  const float* wc   = (const float*)d_in[6];
  const float* bias = (const float*)d_in[7];
  const int*   hidx = (const int*)d_in[8];
  float* out = (float*)d_out;
  char* ws = (char*)d_ws;

  u32* Hbits   = (u32*)(ws + OFF_HBITS);
  u32* HbitsT  = (u32*)(ws + OFF_HBITST);
  u32* Abits   = (u32*)(ws + OFF_ABITS);
  float* Wh1   = (float*)(ws + OFF_WH1);
  float* Wh2   = (float*)(ws + OFF_WH2);
  float* V     = (float*)(ws + OFF_V);
  float* RsInv = (float*)(ws + OFF_RSINV);
  u16* Wcat    = (u16*)(ws + OFF_WCAT);
  u16* W23p    = Wcat + 3 * 65536;   // rows 768..1023 of G0's B-cat
  u16* W3b     = Wcat + 4 * 65536;
  u16* W2b     = Wcat + 5 * 65536;
  u16* Xb      = (u16*)(ws + OFF_XB);
  u16* Whg     = (u16*)(ws + OFF_WHG);
  u16* X4att   = (u16*)(ws + OFF_X4ATT);
  u16* Yb      = (u16*)(ws + OFF_YB);
  u16* XwT     = (u16*)(ws + OFF_XWT);
  u16* WhgTa   = (u16*)(ws + OFF_WHGTA);
  u16* HbT     = (u16*)(ws + OFF_HBT);
  u16* WhgTb   = (u16*)(ws + OFF_WHGTB);
  u16* ExpA    = (u16*)(ws + OFF_EXPA);
  u16* Att1    = (u16*)(ws + OFF_ATT1);
  u16* Att1T   = (u16*)(ws + OFF_ATT1T);
  u16* Att2hn  = (u16*)(ws + OFF_ATT2HN);
  u16* G2h     = (u16*)(ws + OFF_G2H);
  u16* G2hT    = (u16*)(ws + OFF_G2HT);
  u16* Att2hnT = (u16*)(ws + OFF_ATT2HNT);
  u16* Attn2   = (u16*)(ws + OFF_ATTN2);
  float* C1    = (float*)(ws + OFF_C1);
  float* C2    = (float*)(ws + OFF_C2);
  float* G1    = (float*)(ws + OFF_G1);
  u16* Edge    = (u16*)(ws + OFF_EDGE);
  u16* EdgeT   = (u16*)(ws + OFF_EDGET);
  u16* Hn2T    = (u16*)(ws + OFF_HN2T);
  u16* Edge2T  = (u16*)(ws + OFF_EDGE2T);
  float* EdgeAcc = (float*)(ws + OFF_EDGEACC);
  float* Hn2Acc  = (float*)(ws + OFF_HN2ACC);

  dim3 tb(32, 8);

  // --- zero-init: bitsets | H^T | split-K accumulators ---
  hipMemsetAsync(ws + OFF_HBITS, 0, 4 * MB, stream);
  hipMemsetAsync(ws + OFF_HBT, 0, 16 * MB, stream);
  hipMemsetAsync(ws + OFF_EDGEACC, 0, 6 * MB, stream);

  k_diag<<<16, 256, 0, stream>>>(Abits);
  k_scatter<<<256, 256, 0, stream>>>(hidx, Hbits, HbitsT, HbT);
  k_wcast<<<1280, 256, 0, stream>>>(wg, w2, w1, w3, Wcat);
  k_cast<<<4096, 256, 0, stream>>>(x, Xb);

  // --- W23' = w3 @ w2^T (tiny), folded as rows 768..1023 of G0's B ---
  gemm_nt<64, 64, 1><<<16, 256, 0, stream>>>(W3b, W2b, 256, 256, EpiBf16{W23p, 256});

  // --- G0: x @ [wgT|w2T|w1T|W23'] -> Whg(+T,+T) | X4att | XwT+bias | Yb ---
  gemm_nt<128, 128, 1><<<32 * 8, 256, 0, stream>>>(
      Xb, Wcat, 1024, 256, EpiG0{Whg, WhgTa, WhgTb, X4att, XwT, Yb, bias});
  k_rowdots<<<1024, 256, 0, stream>>>(Whg, X4att, ag, wc, Wh1, Wh2, V);

  // --- A = (H@H^T>0) via cliques; expA rows + 1/rowsum ---
  k_clique<<<EE, 256, 0, stream>>>(HbitsT, Abits);
  k_exprows<<<NN, 256, 0, stream>>>(Abits, Wh1, Wh2, ExpA, RsInv);

  // --- big fused GEMM: attention_g @ [H | Wh_g] -> G2h + G2hT + G1 ---
  gemm_nt<128, 128, 1><<<32 * 18, 256, 0, stream>>>(
      ExpA, HbT, 2304, NN, EpiBig{RsInv, G2h, G2hT, G1});

  // --- att1 per edge; transpose for C2 ---
  k_edge_softmax<<<EE, 256, 0, stream>>>(G2hT, HbitsT, V, Att1);
  k_transpose<<<dim3(128, 64), tb, 0, stream>>>(Att1, Att1T, EE, NN);

  // --- [edge|edge2] = att1 @ [xw|Whg], split-K x4 into f32 acc ---
  gemm_nt<64, 64, 4><<<32 * 8 * 4, 256, 0, stream>>>(
      Att1, XwT, 512, NN, EpiAtomF32{EdgeAcc, 512});
  k_cast_edge<<<dim3(16, 64), tb, 0, stream>>>(EdgeAcc, Edge, EdgeT, Edge2T);

  // --- attn2 = (x@W23'^T) @ edge^T / temp ---
  gemm_nt<128, 128, 1><<<32 * 16, 256, 0, stream>>>(
      Yb, Edge, EE, 256, EpiBf16Scale{Attn2, EE, 1.0f / 16.0f});

  // --- att2hn per node ---
  k_node_softmax<<<NN, 256, 0, stream>>>(G2h, Attn2, Hbits, Att2hn);
  hipMemsetAsync(ws + OFF_C1, 0, 12 * MB, stream);   // C1|C2 (Attn2 dead)
  k_transpose<<<dim3(64, 128), tb, 0, stream>>>(Att2hn, Att2hnT, NN, EE);

  // --- hn2 = att2hn^T @ Wh_g, split-K x8 ---
  gemm_nt<64, 64, 8><<<32 * 4 * 8, 256, 0, stream>>>(
      Att2hnT, WhgTa, 256, NN, EpiAtomF32{Hn2Acc, 256});
  k_cast_hn2<<<dim3(8, 64), tb, 0, stream>>>(Hn2Acc, Hn2T);

  // --- C1 = att2hn @ [edge|hn2] (split-K x2); C2 = att1^T @ edge2 (x4) ---
  gemm_nt<64, 64, 2><<<64 * 8 * 2, 256, 0, stream>>>(
      Att2hn, EdgeT, 512, EE, EpiAtomF32{C1, 512});
  gemm_nt<64, 64, 4><<<64 * 4 * 4, 256, 0, stream>>>(
      Att1T, Edge2T, 256, EE, EpiAtomF32{C2, 256});

  // --- node = relu(C1[:, :256]); h_prime = elu(G1 + C1[:,256:] + C2) ---
  k_combine<<<4096, 256, 0, stream>>>(C1, C2, G1, out);
}

// Round 3
// 425.955 us; speedup vs baseline: 1.1381x; 1.0464x over previous
//
#include <hip/hip_runtime.h>
#include <cstdint>
#include <cstddef>

// ============================================================================
// ProposedConv hypergraph dual-attention (round 3):
//  - big GEMM: BN=96 -> grid 768 = exactly 3 blocks/CU (LB 3), no tail round
//  - thin split-K GEMMs: 128x64 tiles (9 ds-cyc/MFMA vs 12 at 64x64), grids
//    of exactly 512 at LB 3; same atomic volume as round 2
//  - launch trim: diag+scatter merged, wcast+cast merged, C1/C2 zeroing
//    folded into the Att2hn transpose kernel
// ============================================================================

#define DI __device__ __forceinline__
typedef unsigned short u16;
typedef unsigned int   u32;
typedef __bf16 bf16x8 __attribute__((ext_vector_type(8)));
typedef float  f32x4  __attribute__((ext_vector_type(4)));

constexpr int NN  = 4096;   // nodes
constexpr int EE  = 2048;   // hyperedges
constexpr int NNZb = 65536; // incidence nnz

// ---------------- workspace layout (bytes), peak 126 MB ----------------
constexpr size_t MB = (size_t)1 << 20;
constexpr size_t OFF_HBITS   = 0;          // u32 [4096][64]   (1 MB)
constexpr size_t OFF_HBITST  = 1*MB;       // u32 [2048][128]  (1 MB)
constexpr size_t OFF_ABITS   = 2*MB;       // u32 [4096][128]  (2 MB); Edge bf16 reuses after
constexpr size_t OFF_EDGE    = 2*MB;       //   bf16 [2048][256] (Abits dead after k_exprows)
constexpr size_t OFF_WH1     = 4*MB;
constexpr size_t OFF_WH2     = 4*MB + 16384;
constexpr size_t OFF_V       = 4*MB + 32768;
constexpr size_t OFF_RSINV   = 4*MB + 49152;
constexpr size_t OFF_WCAT    = 5*MB;       // bf16: [wgT|w2T|w1T|W23'] (1024x256) + w3b + w2b
constexpr size_t OFF_XB      = 6*MB;       // bf16 [4096][256]; then EdgeT [6,7), Hn2T [7,8)
constexpr size_t OFF_EDGET   = 6*MB;       //   bf16 [256][2048]
constexpr size_t OFF_HN2T    = 7*MB;       //   bf16 [256][2048]  ([EdgeT|Hn2T] = C1's B-cat)
constexpr size_t OFF_WHG     = 8*MB;       // bf16 [4096][256]
constexpr size_t OFF_X4ATT   = 10*MB;      // bf16 [4096][256]
constexpr size_t OFF_YB      = 12*MB;      // bf16 [4096][256]  Y = x @ W23'^T
constexpr size_t OFF_XWT     = 14*MB;      // bf16 [256][4096]  ([XwT|WhgTa] = edge's B-cat)
constexpr size_t OFF_WHGTA   = 16*MB;      // bf16 [256][4096]
constexpr size_t OFF_HBT     = 18*MB;      // bf16 [2048][4096]; Edge2T reuses after big GEMM
constexpr size_t OFF_EDGE2T  = 18*MB;      //   bf16 [256][2048]
constexpr size_t OFF_WHGTB   = 34*MB;      // bf16 [256][4096]  ([HbT|WhgTb] = big GEMM's B-cat)
constexpr size_t OFF_EXPA    = 36*MB;      // bf16 [4096][4096]; dead after big GEMM
constexpr size_t OFF_ATT1    = 36*MB;      //   bf16 [2048][4096]; dead after edge GEMM
constexpr size_t OFF_ATT2HN  = 36*MB;      //   bf16 [4096][2048]
constexpr size_t OFF_ATT1T   = 52*MB;      // bf16 [4096][2048]
constexpr size_t OFF_G2H     = 68*MB;      // bf16 [4096][2048]
constexpr size_t OFF_G2HT    = 84*MB;      // bf16 [2048][4096]; dead after edge_softmax
constexpr size_t OFF_ATT2HNT = 84*MB;      //   bf16 [2048][4096]
constexpr size_t OFF_ATTN2   = 100*MB;     // bf16 [4096][2048]; dead after node_softmax
constexpr size_t OFF_C1      = 100*MB;     //   f32 [4096][512] (atomic, zeroed in transpose)
constexpr size_t OFF_C2      = 108*MB;     //   f32 [4096][256]
constexpr size_t OFF_G1      = 116*MB;     // f32 [4096][256]
constexpr size_t OFF_EDGEACC = 120*MB;     // f32 [2048][512] (atomic)
constexpr size_t OFF_HN2ACC  = 124*MB;     // f32 [2048][256] (atomic)

// ---------------- helpers ----------------
DI u16 to_bf(float f) {
  union { float f; u32 u; } x; x.f = f;
  u32 r = x.u + 0x7fffu + ((x.u >> 16) & 1u);
  return (u16)(r >> 16);
}
DI float from_bf(u16 h) { union { u32 u; float f; } x; x.u = (u32)h << 16; return x.f; }
DI void store_bf4(u16* p, float a, float b, float c, float d) {  // 8B aligned store
  u32 lo = (u32)to_bf(a) | ((u32)to_bf(b) << 16);
  u32 hi = (u32)to_bf(c) | ((u32)to_bf(d) << 16);
  *(u32*)p = lo; *((u32*)p + 1) = hi;
}

DI float wredf(float v) {
  #pragma unroll
  for (int o = 32; o; o >>= 1) v += __shfl_down(v, o);
  return v;
}
DI int wredi(int v) {
  #pragma unroll
  for (int o = 32; o; o >>= 1) v += __shfl_down(v, o);
  return v;
}

typedef __attribute__((address_space(3))) void lds_void;
typedef __attribute__((address_space(1))) void glb_void;
DI void async_load16(const void* g, void* l) {
  __builtin_amdgcn_global_load_lds((glb_void*)(uintptr_t)g,
                                   (lds_void*)(u32)(uintptr_t)l, 16, 0, 0);
}

// ---------------- generic NT bf16 GEMM with split-K ----------------
// C[m][n] = sum_k A[m][k]*B[n][k]; A:[M,K] B:[N,K] row-major bf16.
// Grid = (M/BM)*(N/BN)*S blocks; split s handles K-range [s*K/S,(s+1)*K/S).
// Epi called as epi(rb, c, f32x4) covering rows rb..rb+3, column c.
// BM%64==0 (AI>=1 exact), BN%32==0 with BN*8%256==0.
template <int BM, int BN, int S, int LB, class Epi>
__global__ __launch_bounds__(256, LB)
void gemm_nt(const u16* __restrict__ A, const u16* __restrict__ B,
             int N, int K, Epi epi)
{
  constexpr int BK = 64;
  constexpr int WM = BM / 2, WN = BN / 2;
  constexpr int FM = WM / 16, FN = WN / 16;
  constexpr int AI = (BM * 8) / 256, BI = (BN * 8) / 256;
  __shared__ __align__(16) u16 As[BM * BK];
  __shared__ __align__(16) u16 Bs[BN * BK];

  const int tid = threadIdx.x;
  const int w = tid >> 6, l = tid & 63;
  const int nb = N / BN;
  const int tilesPer = gridDim.x / S;
  int t = blockIdx.x;
  const int s = t / tilesPer; t -= s * tilesPer;
  const int bi = t / nb, bj = t - bi * nb;
  const int i0 = bi * BM, j0 = bj * BN;
  const int kLen = K / S, k0 = s * kLen;
  const int wm = (w & 1) * WM, wn = (w >> 1) * WN;
  const int quad = l >> 4, m16 = l & 15;

  f32x4 acc[FM][FN] = {};

  for (int kb = k0; kb < k0 + kLen; kb += BK) {
    __syncthreads();
    #pragma unroll
    for (int i = 0; i < AI; ++i) {
      const int ci = (i * 4 + w) * 64 + l;
      const int r = ci >> 3;
      const int lc = (ci & 7) ^ (r & 7);
      async_load16(A + (size_t)(i0 + r) * K + kb + lc * 8, &As[(i * 4 + w) * 512]);
    }
    #pragma unroll
    for (int i = 0; i < BI; ++i) {
      const int ci = (i * 4 + w) * 64 + l;
      const int r = ci >> 3;
      const int lc = (ci & 7) ^ (r & 7);
      async_load16(B + (size_t)(j0 + r) * K + kb + lc * 8, &Bs[(i * 4 + w) * 512]);
    }
    __syncthreads();
    #pragma unroll
    for (int ks = 0; ks < 2; ++ks) {
      bf16x8 af[FM], bfv[FN];
      #pragma unroll
      for (int mi = 0; mi < FM; ++mi) {
        const int row = wm + mi * 16 + m16;
        af[mi] = *(const bf16x8*)&As[row * BK + (((ks * 4 + quad) ^ (row & 7)) * 8)];
      }
      #pragma unroll
      for (int ni = 0; ni < FN; ++ni) {
        const int row = wn + ni * 16 + m16;
        bfv[ni] = *(const bf16x8*)&Bs[row * BK + (((ks * 4 + quad) ^ (row & 7)) * 8)];
      }
      #pragma unroll
      for (int mi = 0; mi < FM; ++mi)
        #pragma unroll
        for (int ni = 0; ni < FN; ++ni)
          acc[mi][ni] = __builtin_amdgcn_mfma_f32_16x16x32_bf16(
              af[mi], bfv[ni], acc[mi][ni], 0, 0, 0);
    }
  }
  // C/D layout: col = lane&15, row = quad*4 + reg
  #pragma unroll
  for (int mi = 0; mi < FM; ++mi)
    #pragma unroll
    for (int ni = 0; ni < FN; ++ni) {
      const int rb = i0 + wm + mi * 16 + quad * 4;
      const int c  = j0 + wn + ni * 16 + m16;
      epi(rb, c, acc[mi][ni]);
    }
}

// ---------------- epilogues (rb..rb+3 rows, col c) ----------------
struct EpiG0 {   // x @ [wgT|w2T|w1T|W23']: Whg(+2 transposed) | X4att | XwT(+bias) | Yb
  u16 *whg, *whgTa, *whgTb, *x4, *xwT, *yb; const float* bias;
  DI void operator()(int r, int c, f32x4 v) const {
    if (c < 256) {
      #pragma unroll
      for (int i = 0; i < 4; ++i) whg[(r + i) * 256 + c] = to_bf(v[i]);
      store_bf4(&whgTa[(size_t)c * NN + r], v[0], v[1], v[2], v[3]);
      store_bf4(&whgTb[(size_t)c * NN + r], v[0], v[1], v[2], v[3]);
    } else if (c < 512) {
      #pragma unroll
      for (int i = 0; i < 4; ++i) x4[(r + i) * 256 + (c - 256)] = to_bf(v[i]);
    } else if (c < 768) {
      float b = bias[c - 512];
      store_bf4(&xwT[(size_t)(c - 512) * NN + r], v[0]+b, v[1]+b, v[2]+b, v[3]+b);
    } else {
      #pragma unroll
      for (int i = 0; i < 4; ++i) yb[(r + i) * 256 + (c - 768)] = to_bf(v[i]);
    }
  }
};
struct EpiBig {  // expA @ [H|Whg] * (1/rowsum) -> G2h + G2hT + G1
  const float* rsInv; u16* g2h; u16* g2hT; float* g1;
  DI void operator()(int r, int c, f32x4 v) const {
    float w0 = v[0]*rsInv[r], w1 = v[1]*rsInv[r+1], w2 = v[2]*rsInv[r+2], w3 = v[3]*rsInv[r+3];
    if (c < 2048) {
      g2h[(size_t)r * EE + c] = to_bf(w0);
      g2h[(size_t)(r+1) * EE + c] = to_bf(w1);
      g2h[(size_t)(r+2) * EE + c] = to_bf(w2);
      g2h[(size_t)(r+3) * EE + c] = to_bf(w3);
      store_bf4(&g2hT[(size_t)c * NN + r], w0, w1, w2, w3);
    } else {
      g1[(r) * 256 + (c - 2048)] = w0;
      g1[(r+1) * 256 + (c - 2048)] = w1;
      g1[(r+2) * 256 + (c - 2048)] = w2;
      g1[(r+3) * 256 + (c - 2048)] = w3;
    }
  }
};
struct EpiAtomF32 { float* out; int ldn;
  DI void operator()(int r, int c, f32x4 v) const {
    #pragma unroll
    for (int i = 0; i < 4; ++i) atomicAdd(&out[(size_t)(r + i) * ldn + c], v[i]);
  } };
struct EpiBf16 { u16* out; int ldn;
  DI void operator()(int r, int c, f32x4 v) const {
    #pragma unroll
    for (int i = 0; i < 4; ++i) out[(size_t)(r + i) * ldn + c] = to_bf(v[i]);
  } };
struct EpiBf16Scale { u16* out; int ldn; float s;
  DI void operator()(int r, int c, f32x4 v) const {
    #pragma unroll
    for (int i = 0; i < 4; ++i) out[(size_t)(r + i) * ldn + c] = to_bf(v[i] * s);
  } };

// ---------------- small kernels ----------------
__global__ void k_scatter_diag(const int* __restrict__ hidx, u32* hbits, u32* hbitsT,
                               u16* hbT, u32* abits) {
  int k = blockIdx.x * 256 + threadIdx.x;
  if (k < NNZb) {
    int n = hidx[k], e = hidx[NNZb + k];
    atomicOr(&hbits[n * 64 + (e >> 5)], 1u << (e & 31));
    atomicOr(&hbitsT[e * 128 + (n >> 5)], 1u << (n & 31));
    hbT[(size_t)e * NN + n] = 0x3F80;            // bf16 1.0
  } else {
    int i = k - NNZb;
    if (i < NN) atomicOr(&abits[i * 128 + (i >> 5)], 1u << (i & 31));
  }
}

__global__ void k_prep(const float* wg, const float* w2, const float* w1,
                       const float* w3, const float* x, u16* wcat, u16* xb) {
  int idx = blockIdx.x * 256 + threadIdx.x;      // 5*65536 + 1048576
  if (idx < 3 * 65536) {
    int blk = idx >> 16, r = idx & 65535;
    int d = r >> 8, kk = r & 255;
    const float* src = blk == 0 ? wg : blk == 1 ? w2 : w1;
    wcat[idx] = to_bf(src[kk * 256 + d]);        // transposed
  } else if (idx < 4 * 65536) {
    int r = idx & 65535;
    wcat[4 * 65536 + r] = to_bf(w3[r]);          // w3b straight
  } else if (idx < 5 * 65536) {
    int r = idx & 65535;
    wcat[5 * 65536 + r] = to_bf(w2[r]);          // w2b straight
  } else {
    int r = idx - 5 * 65536;
    xb[r] = to_bf(x[r]);
  }
}

__global__ void k_rowdots(const u16* __restrict__ whg, const u16* __restrict__ x4,
                          const float* __restrict__ ag, const float* __restrict__ wc,
                          float* wh1, float* wh2, float* v) {
  int wv = threadIdx.x >> 6, l = threadIdx.x & 63;
  int row = blockIdx.x * 4 + wv;
  float s1 = 0, s2 = 0, s3 = 0;
  #pragma unroll
  for (int dd = 0; dd < 4; ++dd) {
    int d = l * 4 + dd;
    float a = from_bf(whg[row * 256 + d]);
    s1 += a * ag[d]; s2 += a * ag[256 + d];
    s3 += from_bf(x4[row * 256 + d]) * wc[d];
  }
  s1 = wredf(s1); s2 = wredf(s2); s3 = wredf(s3);
  if (l == 0) { wh1[row] = s1; wh2[row] = s2; v[row] = s3 * (1.0f / 16.0f); }
}

__global__ void k_clique(const u32* __restrict__ hbitsT, u32* abits) {
  int e = blockIdx.x, tid = threadIdx.x;
  __shared__ int list[512];
  __shared__ int cnt;
  if (tid == 0) cnt = 0;
  __syncthreads();
  if (tid < 128) {
    u32 w = hbitsT[e * 128 + tid];
    while (w) {
      int b = __ffs(w) - 1;
      int p = atomicAdd(&cnt, 1);
      if (p < 512) list[p] = tid * 32 + b;
      w &= w - 1;
    }
  }
  __syncthreads();
  int c = cnt < 512 ? cnt : 512;
  for (int p = tid; p < c * c; p += 256) {
    int i = list[p / c], j = list[p % c];
    atomicOr(&abits[i * 128 + (j >> 5)], 1u << (j & 31));
  }
}

__global__ void k_exprows(const u32* __restrict__ abits, const float* __restrict__ wh1,
                          const float* __restrict__ wh2, u16* __restrict__ expA,
                          float* rsInv) {
  int i = blockIdx.x, tid = threadIdx.x;
  __shared__ float w2s[NN];
  __shared__ float ssum;
  for (int j = tid; j < NN; j += 256) w2s[j] = wh2[j];
  if (tid == 0) ssum = 0.f;
  __syncthreads();
  float a = wh1[i], lsum = 0.f;
  for (int j = tid; j < NN; j += 256) {
    u32 w = abits[i * 128 + (j >> 5)];
    u16 h = 0;
    if ((w >> (j & 31)) & 1) {
      float z = a + w2s[j];
      float eg = z > 0.f ? z : 0.2f * z;
      h = to_bf(__expf(eg));
      lsum += from_bf(h);
    }
    expA[(size_t)i * NN + j] = h;
  }
  lsum = wredf(lsum);
  if ((tid & 63) == 0) atomicAdd(&ssum, lsum);
  __syncthreads();
  if (tid == 0) rsInv[i] = 1.0f / ssum;
}

__global__ void k_edge_softmax(const u16* __restrict__ g2hT, const u32* __restrict__ hbitsT,
                               const float* __restrict__ v, u16* __restrict__ att1) {
  int e = blockIdx.x, tid = threadIdx.x;
  __shared__ float evals[NN];
  __shared__ u32 hw[128];
  __shared__ float s1s, s2s; __shared__ int cs;
  if (tid == 0) { s1s = 0.f; s2s = 0.f; cs = 0; }
  if (tid < 128) hw[tid] = hbitsT[e * 128 + tid];
  __syncthreads();
  float sum1 = 0.f;
  for (int j = tid; j < NN; j += 256) {
    float ev = __expf(from_bf(g2hT[(size_t)e * NN + j]));
    evals[j] = ev; sum1 += ev;
  }
  float sum2 = 0.f; int cnt = 0;
  if (tid < 128) {
    u32 w = hw[tid]; cnt = __popc(w);
    while (w) { int b = __ffs(w) - 1; sum2 += __expf(v[tid * 32 + b]); w &= w - 1; }
  }
  sum1 = wredf(sum1); sum2 = wredf(sum2); cnt = wredi(cnt);
  if ((tid & 63) == 0) { atomicAdd(&s1s, sum1); atomicAdd(&s2s, sum2); atomicAdd(&cs, cnt); }
  __syncthreads();
  float inv1 = 1.0f / s1s;
  int c = cs;
  float inv2 = c > 0 ? 1.0f / s2s : 0.0f;
  float unif = c > 0 ? 0.0f : (1.0f / (float)NN);
  for (int j = tid; j < NN; j += 256) {
    float t = evals[j] * inv1 + unif;
    if ((hw[j >> 5] >> (j & 31)) & 1) t += __expf(v[j]) * inv2;
    att1[(size_t)e * NN + j] = to_bf(t);
  }
}

__global__ void k_node_softmax(const u16* __restrict__ g2h, const u16* __restrict__ attn2,
                               const u32* __restrict__ hbits, u16* __restrict__ att2hn) {
  int n = blockIdx.x, tid = threadIdx.x;
  __shared__ float ev3[EE], ev4[EE];
  __shared__ u32 hw[64];
  __shared__ float s3s, s4s; __shared__ int cs;
  if (tid == 0) { s3s = 0.f; s4s = 0.f; cs = 0; }
  if (tid < 64) hw[tid] = hbits[n * 64 + tid];
  __syncthreads();
  float s3 = 0.f, s4 = 0.f; int cl = 0;
  for (int e = tid; e < EE; e += 256) {
    float x3 = __expf(from_bf(g2h[(size_t)n * EE + e]));
    ev3[e] = x3; s3 += x3;
    bool m = (hw[e >> 5] >> (e & 31)) & 1;
    float x4 = m ? __expf(from_bf(attn2[(size_t)n * EE + e])) : 0.f;
    ev4[e] = x4; s4 += x4; cl += m;
  }
  s3 = wredf(s3); s4 = wredf(s4); cl = wredi(cl);
  if ((tid & 63) == 0) { atomicAdd(&s3s, s3); atomicAdd(&s4s, s4); atomicAdd(&cs, cl); }
  __syncthreads();
  float inv3 = 1.0f / s3s;
  int c = cs;
  float inv4 = c > 0 ? 1.0f / s4s : 0.0f;
  float unif = c > 0 ? 0.0f : (1.0f / (float)EE);
  for (int e = tid; e < EE; e += 256)
    att2hn[(size_t)n * EE + e] = to_bf(ev3[e] * inv3 + ev4[e] * inv4 + unif);
}

// transpose; optionally zero zcount floats of zb per block (fused memset)
__global__ void k_transpose(const u16* __restrict__ in, u16* __restrict__ out,
                            int R, int C, float* zb, int zcount) {
  __shared__ u16 t[32][33];
  int x0 = blockIdx.x * 32, y0 = blockIdx.y * 32;
  int tx = threadIdx.x, ty = threadIdx.y;
  if (zb) {
    int tid = ty * 32 + tx;
    size_t base = (size_t)(blockIdx.y * gridDim.x + blockIdx.x) * zcount;
    for (int j = tid; j < zcount; j += 256) zb[base + j] = 0.f;
  }
  #pragma unroll
  for (int k = 0; k < 32; k += 8)
    t[ty + k][tx] = in[(size_t)(y0 + ty + k) * C + x0 + tx];
  __syncthreads();
  #pragma unroll
  for (int k = 0; k < 32; k += 8)
    out[(size_t)(x0 + ty + k) * R + y0 + tx] = t[tx][ty + k];
}

// EdgeAcc f32 [2048,512] -> Edge bf16 (cols<256), EdgeT, Edge2T (transposed)
__global__ void k_cast_edge(const float* __restrict__ acc, u16* edge,
                            u16* edgeT, u16* edge2T) {
  __shared__ float t[32][33];
  int c0 = blockIdx.x * 32, r0 = blockIdx.y * 32;
  int tx = threadIdx.x, ty = threadIdx.y;
  #pragma unroll
  for (int k = 0; k < 32; k += 8) {
    float v = acc[(size_t)(r0 + ty + k) * 512 + c0 + tx];
    t[ty + k][tx] = v;
    if (c0 < 256) edge[(r0 + ty + k) * 256 + c0 + tx] = to_bf(v);
  }
  __syncthreads();
  u16* dst = c0 < 256 ? edgeT : edge2T;
  int cc0 = c0 & 255;
  #pragma unroll
  for (int k = 0; k < 32; k += 8)
    dst[(size_t)(cc0 + ty + k) * EE + r0 + tx] = to_bf(t[tx][ty + k]);
}

// Hn2Acc f32 [2048,256] -> Hn2T bf16 [256,2048]
__global__ void k_cast_hn2(const float* __restrict__ acc, u16* hn2T) {
  __shared__ float t[32][33];
  int c0 = blockIdx.x * 32, r0 = blockIdx.y * 32;
  int tx = threadIdx.x, ty = threadIdx.y;
  #pragma unroll
  for (int k = 0; k < 32; k += 8)
    t[ty + k][tx] = acc[(size_t)(r0 + ty + k) * 256 + c0 + tx];
  __syncthreads();
  #pragma unroll
  for (int k = 0; k < 32; k += 8)
    hn2T[(size_t)(c0 + ty + k) * EE + r0 + tx] = to_bf(t[tx][ty + k]);
}

__global__ void k_combine(const float* __restrict__ C1, const float* __restrict__ C2,
                          const float* __restrict__ G1, float* __restrict__ out) {
  int idx = blockIdx.x * 256 + threadIdx.x;     // 4096*256
  int r = idx >> 8, d = idx & 255;
  float nodev = C1[r * 512 + d];
  out[idx] = nodev > 0.f ? nodev : 0.f;                       // ReLU
  float s = G1[idx] + C1[r * 512 + 256 + d] + C2[idx];
  out[1048576 + idx] = s > 0.f ? s : expm1f(s);               // ELU
}

// ---------------- launch ----------------
extern "C" void kernel_launch(void* const* d_in, const int* in_sizes, int n_in,
                              void* d_out, int out_size, void* d_ws, size_t ws_size,
                              hipStream_t stream) {
  (void)in_sizes; (void)n_in; (void)out_size; (void)ws_size;
  const float* x    = (const float*)d_in[0];
  const float* w1   = (const float*)d_in[1];
  const float* w2   = (const float*)d_in[2];
  const float* w3   = (const float*)d_in[3];
  const float* wg   = (const float*)d_in[4];
  const float* ag   = (const float*)d_in[5];
  const float* wc   = (const float*)d_in[6];
  const float* bias = (const float*)d_in[7];
  const int*   hidx = (const int*)d_in[8];
  float* out = (float*)d_out;
  char* ws = (char*)d_ws;

  u32* Hbits   = (u32*)(ws + OFF_HBITS);
  u32* HbitsT  = (u32*)(ws + OFF_HBITST);
  u32* Abits   = (u32*)(ws + OFF_ABITS);
  float* Wh1   = (float*)(ws + OFF_WH1);
  float* Wh2   = (float*)(ws + OFF_WH2);
  float* V     = (float*)(ws + OFF_V);
  float* RsInv = (float*)(ws + OFF_RSINV);
  u16* Wcat    = (u16*)(ws + OFF_WCAT);
  u16* W23p    = Wcat + 3 * 65536;   // rows 768..1023 of G0's B-cat
  u16* W3b     = Wcat + 4 * 65536;
  u16* W2b     = Wcat + 5 * 65536;
  u16* Xb      = (u16*)(ws + OFF_XB);
  u16* Whg     = (u16*)(ws + OFF_WHG);
  u16* X4att   = (u16*)(ws + OFF_X4ATT);
  u16* Yb      = (u16*)(ws + OFF_YB);
  u16* XwT     = (u16*)(ws + OFF_XWT);
  u16* WhgTa   = (u16*)(ws + OFF_WHGTA);
  u16* HbT     = (u16*)(ws + OFF_HBT);
  u16* WhgTb   = (u16*)(ws + OFF_WHGTB);
  u16* ExpA    = (u16*)(ws + OFF_EXPA);
  u16* Att1    = (u16*)(ws + OFF_ATT1);
  u16* Att1T   = (u16*)(ws + OFF_ATT1T);
  u16* Att2hn  = (u16*)(ws + OFF_ATT2HN);
  u16* G2h     = (u16*)(ws + OFF_G2H);
  u16* G2hT    = (u16*)(ws + OFF_G2HT);
  u16* Att2hnT = (u16*)(ws + OFF_ATT2HNT);
  u16* Attn2   = (u16*)(ws + OFF_ATTN2);
  float* C1    = (float*)(ws + OFF_C1);
  float* C2    = (float*)(ws + OFF_C2);
  float* G1    = (float*)(ws + OFF_G1);
  u16* Edge    = (u16*)(ws + OFF_EDGE);
  u16* EdgeT   = (u16*)(ws + OFF_EDGET);
  u16* Hn2T    = (u16*)(ws + OFF_HN2T);
  u16* Edge2T  = (u16*)(ws + OFF_EDGE2T);
  float* EdgeAcc = (float*)(ws + OFF_EDGEACC);
  float* Hn2Acc  = (float*)(ws + OFF_HN2ACC);

  dim3 tb(32, 8);

  // --- zero-init: bitsets | H^T | split-K accumulators ---
  hipMemsetAsync(ws + OFF_HBITS, 0, 4 * MB, stream);
  hipMemsetAsync(ws + OFF_HBT, 0, 16 * MB, stream);
  hipMemsetAsync(ws + OFF_EDGEACC, 0, 6 * MB, stream);

  k_scatter_diag<<<272, 256, 0, stream>>>(hidx, Hbits, HbitsT, HbT, Abits);
  k_prep<<<5376, 256, 0, stream>>>(wg, w2, w1, w3, x, Wcat, Xb);

  // --- W23' = w3 @ w2^T (tiny), folded as rows 768..1023 of G0's B ---
  gemm_nt<64, 64, 1, 2><<<16, 256, 0, stream>>>(W3b, W2b, 256, 256, EpiBf16{W23p, 256});

  // --- G0: x @ [wgT|w2T|w1T|W23'] -> Whg(+T,+T) | X4att | XwT+bias | Yb ---
  gemm_nt<128, 64, 1, 3><<<512, 256, 0, stream>>>(
      Xb, Wcat, 1024, 256, EpiG0{Whg, WhgTa, WhgTb, X4att, XwT, Yb, bias});
  k_rowdots<<<1024, 256, 0, stream>>>(Whg, X4att, ag, wc, Wh1, Wh2, V);

  // --- A = (H@H^T>0) via cliques; expA rows + 1/rowsum ---
  k_clique<<<EE, 256, 0, stream>>>(HbitsT, Abits);
  k_exprows<<<NN, 256, 0, stream>>>(Abits, Wh1, Wh2, ExpA, RsInv);

  // --- big fused GEMM: attention_g @ [H | Wh_g] -> G2h + G2hT + G1 ---
  // BN=96: grid 32x24 = 768 = exactly 3 blocks/CU, no tail round
  gemm_nt<128, 96, 1, 3><<<768, 256, 0, stream>>>(
      ExpA, HbT, 2304, NN, EpiBig{RsInv, G2h, G2hT, G1});

  // --- att1 per edge; transpose for C2 ---
  k_edge_softmax<<<EE, 256, 0, stream>>>(G2hT, HbitsT, V, Att1);
  k_transpose<<<dim3(128, 64), tb, 0, stream>>>(Att1, Att1T, EE, NN, nullptr, 0);

  // --- [edge|edge2] = att1 @ [xw|Whg], split-K x4 into f32 acc ---
  gemm_nt<128, 64, 4, 3><<<512, 256, 0, stream>>>(
      Att1, XwT, 512, NN, EpiAtomF32{EdgeAcc, 512});
  k_cast_edge<<<dim3(16, 64), tb, 0, stream>>>(EdgeAcc, Edge, EdgeT, Edge2T);

  // --- attn2 = (x@W23'^T) @ edge^T / temp ---
  gemm_nt<128, 128, 1, 2><<<512, 256, 0, stream>>>(
      Yb, Edge, EE, 256, EpiBf16Scale{Attn2, EE, 1.0f / 16.0f});

  // --- att2hn per node; transpose also zeroes C1|C2 (Attn2 dead here) ---
  k_node_softmax<<<NN, 256, 0, stream>>>(G2h, Attn2, Hbits, Att2hn);
  k_transpose<<<dim3(64, 128), tb, 0, stream>>>(Att2hn, Att2hnT, NN, EE,
                                                C1, (12 * MB / 4) / (64 * 128));

  // --- hn2 = att2hn^T @ Wh_g, split-K x8 ---
  gemm_nt<128, 64, 8, 3><<<512, 256, 0, stream>>>(
      Att2hnT, WhgTa, 256, NN, EpiAtomF32{Hn2Acc, 256});
  k_cast_hn2<<<dim3(8, 64), tb, 0, stream>>>(Hn2Acc, Hn2T);

  // --- C1 = att2hn @ [edge|hn2] (split-K x2); C2 = att1^T @ edge2 (x4) ---
  gemm_nt<128, 64, 2, 3><<<512, 256, 0, stream>>>(
      Att2hn, EdgeT, 512, EE, EpiAtomF32{C1, 512});
  gemm_nt<128, 64, 4, 3><<<512, 256, 0, stream>>>(
      Att1T, Edge2T, 256, EE, EpiAtomF32{C2, 256});

  // --- node = relu(C1[:, :256]); h_prime = elu(G1 + C1[:,256:] + C2) ---
  k_combine<<<4096, 256, 0, stream>>>(C1, C2, G1, out);
}

// Round 4
// 395.026 us; speedup vs baseline: 1.2273x; 1.0783x over previous
//
#include <hip/hip_runtime.h>
#include <cstdint>
#include <cstddef>

// ============================================================================
// ProposedConv hypergraph dual-attention (round 4):
//  - all GEMMs S=1, no atomics/memsets/cast kernels: transposed operands are
//    produced directly by reshaped GEMMs (edgeT-cat, hn2T) or epilogues
//  - Yb = x4att @ w3^T replaces the serial W23' pre-GEMM
//  - final combine fused into C1 epilogue (writes d_out directly)
//  - 13 launches total: prep(+zeroing), scatter, G0, rowdots+clique,
//    exprows, bigGEMM, edge_softmax, tri{edgeT,Yb,transpose}, dual{C2,attn2},
//    node_softmax, transpose, hn2T, C1+combine
// ============================================================================

#define DI __device__ __forceinline__
typedef unsigned short u16;
typedef unsigned int   u32;
typedef __bf16 bf16x8 __attribute__((ext_vector_type(8)));
typedef float  f32x4  __attribute__((ext_vector_type(4)));
typedef u32    u32x4  __attribute__((ext_vector_type(4)));

constexpr int NN  = 4096;   // nodes
constexpr int EE  = 2048;   // hyperedges
constexpr int NNZb = 65536; // incidence nnz

// ---------------- workspace layout (bytes) ----------------
constexpr size_t MB = (size_t)1 << 20;
constexpr size_t OFF_HBITS   = 0;          // u32 [4096][64]
constexpr size_t OFF_HBITST  = 1*MB;       // u32 [2048][128]
constexpr size_t OFF_ABITS   = 2*MB;       // u32 [4096][128]; Edge reuses after exprows
constexpr size_t OFF_EDGE    = 2*MB;       //   bf16 [2048][256]
constexpr size_t OFF_WH1     = 4*MB;
constexpr size_t OFF_WH2     = 4*MB + 16384;
constexpr size_t OFF_V       = 4*MB + 32768;
constexpr size_t OFF_RSINV   = 4*MB + 49152;
constexpr size_t OFF_WCAT    = 5*MB;       // bf16 [wgT|w2T|w1T](768x256) + w3b(256x256)
constexpr size_t OFF_XB      = 6*MB;       // bf16 [4096][256]; EdgeT/Hn2T reuse after G0
constexpr size_t OFF_EDGET   = 6*MB;       //   bf16 [256][2048]
constexpr size_t OFF_HN2T    = 7*MB;       //   bf16 [256][2048] ([EdgeT|Hn2T] = C1 B-cat)
constexpr size_t OFF_WHG     = 8*MB;       // bf16 [4096][256]
constexpr size_t OFF_X4ATT   = 10*MB;      // bf16 [4096][256]
constexpr size_t OFF_YB      = 12*MB;      // bf16 [4096][256]
constexpr size_t OFF_XWT     = 14*MB;      // bf16 [256][4096] ([XwT|WhgTa] = edgeT A-cat)
constexpr size_t OFF_WHGTA   = 16*MB;      // bf16 [256][4096]
constexpr size_t OFF_HBT     = 18*MB;      // bf16 [2048][4096]; Edge2T reuses after bigGEMM
constexpr size_t OFF_EDGE2T  = 18*MB;      //   bf16 [256][2048]
constexpr size_t OFF_WHGTB   = 34*MB;      // bf16 [256][4096] ([HbT|WhgTb] = bigGEMM B-cat)
constexpr size_t OFF_EXPA    = 36*MB;      // bf16 [4096][4096]; dead after bigGEMM
constexpr size_t OFF_ATT1    = 36*MB;      //   bf16 [2048][4096]; dead after edgeT GEMM
constexpr size_t OFF_ATT2HN  = 36*MB;      //   bf16 [4096][2048]
constexpr size_t OFF_ATT1T   = 52*MB;      // bf16 [4096][2048]
constexpr size_t OFF_G2H     = 68*MB;      // bf16 [4096][2048]
constexpr size_t OFF_G2HT    = 84*MB;      // bf16 [2048][4096]; dead after edge_softmax
constexpr size_t OFF_ATT2HNT = 84*MB;      //   bf16 [2048][4096]
constexpr size_t OFF_ATTN2   = 100*MB;     // bf16 [4096][2048]; dead after node_softmax
constexpr size_t OFF_G1      = 116*MB;     // f32 [4096][256]
constexpr size_t OFF_C2      = 120*MB;     // f32 [4096][256]

// ---------------- helpers ----------------
DI u16 to_bf(float f) {
  union { float f; u32 u; } x; x.f = f;
  u32 r = x.u + 0x7fffu + ((x.u >> 16) & 1u);
  return (u16)(r >> 16);
}
DI float from_bf(u16 h) { union { u32 u; float f; } x; x.u = (u32)h << 16; return x.f; }
DI void store_bf4(u16* p, float a, float b, float c, float d) {  // 8B aligned store
  u32 lo = (u32)to_bf(a) | ((u32)to_bf(b) << 16);
  u32 hi = (u32)to_bf(c) | ((u32)to_bf(d) << 16);
  *(u32*)p = lo; *((u32*)p + 1) = hi;
}

DI float wredf(float v) {
  #pragma unroll
  for (int o = 32; o; o >>= 1) v += __shfl_down(v, o);
  return v;
}
DI int wredi(int v) {
  #pragma unroll
  for (int o = 32; o; o >>= 1) v += __shfl_down(v, o);
  return v;
}

typedef __attribute__((address_space(3))) void lds_void;
typedef __attribute__((address_space(1))) void glb_void;
DI void async_load16(const void* g, void* l) {
  __builtin_amdgcn_global_load_lds((glb_void*)(uintptr_t)g,
                                   (lds_void*)(u32)(uintptr_t)l, 16, 0, 0);
}

// ---------------- generic NT bf16 GEMM body (device fn, S=1) --------------
// C[m][n] = sum_k A[m][k]*B[n][k]; A:[M,K] B:[N,K] row-major bf16.
// tile in [0, (M/BM)*nb); epi(rb, c, f32x4) covers rows rb..rb+3, column c.
template <int BM, int BN, class Epi>
DI void gemm_body(const u16* __restrict__ A, const u16* __restrict__ B,
                  int nb, int K, Epi epi, int tile, u16* As, u16* Bs)
{
  constexpr int BK = 64;
  constexpr int WM = BM / 2, WN = BN / 2;
  constexpr int FM = WM / 16, FN = WN / 16;
  constexpr int AI = (BM * 8) / 256, BI = (BN * 8) / 256;

  const int tid = threadIdx.x;
  const int w = tid >> 6, l = tid & 63;
  const int bi = tile / nb, bj = tile - bi * nb;
  const int i0 = bi * BM, j0 = bj * BN;
  const int wm = (w & 1) * WM, wn = (w >> 1) * WN;
  const int quad = l >> 4, m16 = l & 15;

  f32x4 acc[FM][FN] = {};

  for (int kb = 0; kb < K; kb += BK) {
    __syncthreads();
    #pragma unroll
    for (int i = 0; i < AI; ++i) {
      const int ci = (i * 4 + w) * 64 + l;
      const int r = ci >> 3;
      const int lc = (ci & 7) ^ (r & 7);
      async_load16(A + (size_t)(i0 + r) * K + kb + lc * 8, &As[(i * 4 + w) * 512]);
    }
    #pragma unroll
    for (int i = 0; i < BI; ++i) {
      const int ci = (i * 4 + w) * 64 + l;
      const int r = ci >> 3;
      const int lc = (ci & 7) ^ (r & 7);
      async_load16(B + (size_t)(j0 + r) * K + kb + lc * 8, &Bs[(i * 4 + w) * 512]);
    }
    __syncthreads();
    #pragma unroll
    for (int ks = 0; ks < 2; ++ks) {
      bf16x8 af[FM], bfv[FN];
      #pragma unroll
      for (int mi = 0; mi < FM; ++mi) {
        const int row = wm + mi * 16 + m16;
        af[mi] = *(const bf16x8*)&As[row * BK + (((ks * 4 + quad) ^ (row & 7)) * 8)];
      }
      #pragma unroll
      for (int ni = 0; ni < FN; ++ni) {
        const int row = wn + ni * 16 + m16;
        bfv[ni] = *(const bf16x8*)&Bs[row * BK + (((ks * 4 + quad) ^ (row & 7)) * 8)];
      }
      #pragma unroll
      for (int mi = 0; mi < FM; ++mi)
        #pragma unroll
        for (int ni = 0; ni < FN; ++ni)
          acc[mi][ni] = __builtin_amdgcn_mfma_f32_16x16x32_bf16(
              af[mi], bfv[ni], acc[mi][ni], 0, 0, 0);
    }
  }
  // C/D layout: col = lane&15, row = quad*4 + reg
  #pragma unroll
  for (int mi = 0; mi < FM; ++mi)
    #pragma unroll
    for (int ni = 0; ni < FN; ++ni) {
      const int rb = i0 + wm + mi * 16 + quad * 4;
      const int c  = j0 + wn + ni * 16 + m16;
      epi(rb, c, acc[mi][ni]);
    }
}

// 32x32 transpose tile as device fn (flat 256 threads); smem >= 32*33 u16
DI void t32_tile(const u16* __restrict__ in, u16* __restrict__ out,
                 int R, int C, int bx, int by, u16* t) {
  int tx = threadIdx.x & 31, ty = threadIdx.x >> 5;   // 32 x 8
  int x0 = bx * 32, y0 = by * 32;
  #pragma unroll
  for (int k = 0; k < 32; k += 8)
    t[(ty + k) * 33 + tx] = in[(size_t)(y0 + ty + k) * C + x0 + tx];
  __syncthreads();
  #pragma unroll
  for (int k = 0; k < 32; k += 8)
    out[(size_t)(x0 + ty + k) * R + y0 + tx] = t[tx * 33 + ty + k];
}

// ---------------- epilogues (rb..rb+3 rows, col c) ----------------
struct EpiG0 {   // x @ [wgT|w2T|w1T]: Whg(+2 transposed) | X4att | XwT(+bias)
  u16 *whg, *whgTa, *whgTb, *x4, *xwT; const float* bias;
  DI void operator()(int r, int c, f32x4 v) const {
    if (c < 256) {
      #pragma unroll
      for (int i = 0; i < 4; ++i) whg[(r + i) * 256 + c] = to_bf(v[i]);
      store_bf4(&whgTa[(size_t)c * NN + r], v[0], v[1], v[2], v[3]);
      store_bf4(&whgTb[(size_t)c * NN + r], v[0], v[1], v[2], v[3]);
    } else if (c < 512) {
      #pragma unroll
      for (int i = 0; i < 4; ++i) x4[(r + i) * 256 + (c - 256)] = to_bf(v[i]);
    } else {
      float b = bias[c - 512];
      store_bf4(&xwT[(size_t)(c - 512) * NN + r], v[0]+b, v[1]+b, v[2]+b, v[3]+b);
    }
  }
};
struct EpiBig {  // expA @ [H|Whg] * (1/rowsum) -> G2h + G2hT + G1
  const float* rsInv; u16* g2h; u16* g2hT; float* g1;
  DI void operator()(int r, int c, f32x4 v) const {
    float w0 = v[0]*rsInv[r], w1 = v[1]*rsInv[r+1], w2 = v[2]*rsInv[r+2], w3 = v[3]*rsInv[r+3];
    if (c < 2048) {
      g2h[(size_t)r * EE + c] = to_bf(w0);
      g2h[(size_t)(r+1) * EE + c] = to_bf(w1);
      g2h[(size_t)(r+2) * EE + c] = to_bf(w2);
      g2h[(size_t)(r+3) * EE + c] = to_bf(w3);
      store_bf4(&g2hT[(size_t)c * NN + r], w0, w1, w2, w3);
    } else {
      g1[(r) * 256 + (c - 2048)] = w0;
      g1[(r+1) * 256 + (c - 2048)] = w1;
      g1[(r+2) * 256 + (c - 2048)] = w2;
      g1[(r+3) * 256 + (c - 2048)] = w3;
    }
  }
};
struct EpiEdgeT {   // [xwT|WhgTa] @ Att1^T-style: rows<256 -> EdgeT + Edge; else Edge2T
  u16 *edgeT, *edge2T, *edge;
  DI void operator()(int r, int c, f32x4 v) const {
    if (r < 256) {
      #pragma unroll
      for (int i = 0; i < 4; ++i) edgeT[(size_t)(r + i) * EE + c] = to_bf(v[i]);
      store_bf4(&edge[(size_t)c * 256 + r], v[0], v[1], v[2], v[3]);
    } else {
      #pragma unroll
      for (int i = 0; i < 4; ++i) edge2T[(size_t)(r - 256 + i) * EE + c] = to_bf(v[i]);
    }
  }
};
struct EpiCombine { // C1 epilogue: relu(node) | elu(G1 + C2 + v) straight to out
  const float* g1; const float* c2; float* out;
  DI void operator()(int r, int c, f32x4 v) const {
    if (c < 256) {
      #pragma unroll
      for (int i = 0; i < 4; ++i) out[(r + i) * 256 + c] = fmaxf(v[i], 0.f);
    } else {
      int d = c - 256;
      #pragma unroll
      for (int i = 0; i < 4; ++i) {
        float s = g1[(r + i) * 256 + d] + c2[(r + i) * 256 + d] + v[i];
        out[1048576 + (r + i) * 256 + d] = s > 0.f ? s : expm1f(s);
      }
    }
  }
};
struct EpiBf16 { u16* out; int ldn;
  DI void operator()(int r, int c, f32x4 v) const {
    #pragma unroll
    for (int i = 0; i < 4; ++i) out[(size_t)(r + i) * ldn + c] = to_bf(v[i]);
  } };
struct EpiBf16Scale { u16* out; int ldn; float s;
  DI void operator()(int r, int c, f32x4 v) const {
    #pragma unroll
    for (int i = 0; i < 4; ++i) out[(size_t)(r + i) * ldn + c] = to_bf(v[i] * s);
  } };
struct EpiF32 { float* out; int ldn;
  DI void operator()(int r, int c, f32x4 v) const {
    #pragma unroll
    for (int i = 0; i < 4; ++i) out[(size_t)(r + i) * ldn + c] = v[i];
  } };

// ---------------- GEMM wrappers ----------------
template <int BM, int BN, int LB, class Epi>
__global__ __launch_bounds__(256, LB)
void gemm_k(const u16* __restrict__ A, const u16* __restrict__ B,
            int nb, int K, Epi epi) {
  __shared__ __align__(16) u16 smem[(BM + BN) * 64];
  gemm_body<BM, BN>(A, B, nb, K, epi, blockIdx.x, smem, smem + BM * 64);
}

// tri-launch: edgeT-cat GEMM (64x64, 256 tiles) | Yb GEMM (128x64, 128 tiles)
// | Att1 transpose (8192 tiles)
__global__ __launch_bounds__(256, 2)
void k_tri_edge(const u16* __restrict__ Fcat, const u16* __restrict__ Att1,
                EpiEdgeT e0,
                const u16* __restrict__ X4att, const u16* __restrict__ W3b,
                EpiBf16 e1,
                const u16* __restrict__ tin, u16* __restrict__ tout) {
  __shared__ __align__(16) u16 smem[192 * 64];
  int b = blockIdx.x;
  if (b < 256)      gemm_body<64, 64>(Fcat, Att1, 32, 4096, e0, b, smem, smem + 64 * 64);
  else if (b < 384) gemm_body<128, 64>(X4att, W3b, 4, 256, e1, b - 256, smem, smem + 128 * 64);
  else { int t = b - 384; t32_tile(tin, tout, EE, NN, t & 127, t >> 7, smem); }
}

// dual-launch: C2 GEMM (128x64, 128 tiles, K=2048) first | attn2 (128x128, 512)
__global__ __launch_bounds__(256, 2)
void k_dual_attn2(const u16* __restrict__ Att1T, const u16* __restrict__ Edge2T,
                  EpiF32 e0,
                  const u16* __restrict__ Yb, const u16* __restrict__ Edge,
                  EpiBf16Scale e1) {
  __shared__ __align__(16) u16 smem[256 * 64];
  int b = blockIdx.x;
  if (b < 128) gemm_body<128, 64>(Att1T, Edge2T, 4, 2048, e0, b, smem, smem + 128 * 64);
  else         gemm_body<128, 128>(Yb, Edge, 16, 256, e1, b - 128, smem, smem + 128 * 64);
}

// ---------------- small kernels ----------------
__global__ void k_prep(const float* wg, const float* w2, const float* w1,
                       const float* w3, const float* x, u16* wcat, u16* xb,
                       char* zbits, char* zhbt) {
  int idx = blockIdx.x * 256 + threadIdx.x;
  if (blockIdx.x < 5120) {            // casts: 1310720 elements
    if (idx < 196608) {
      int blk = idx >> 16, r = idx & 65535;
      int d = r >> 8, kk = r & 255;
      const float* src = blk == 0 ? wg : blk == 1 ? w2 : w1;
      wcat[idx] = to_bf(src[kk * 256 + d]);        // transposed
    } else if (idx < 262144) {
      int r = idx - 196608;
      wcat[196608 + r] = to_bf(w3[r]);             // w3 straight
    } else {
      int r = idx - 262144;
      xb[r] = to_bf(x[r]);
    }
  } else {                            // zero 4 MB bits + 16 MB HbT (16 B/thread)
    int z = idx - 5120 * 256;
    u32x4 zero = {0, 0, 0, 0};
    if (z < 262144) ((u32x4*)zbits)[z] = zero;
    else            ((u32x4*)zhbt)[z - 262144] = zero;
  }
}

__global__ void k_scatter_diag(const int* __restrict__ hidx, u32* hbits, u32* hbitsT,
                               u16* hbT, u32* abits) {
  int k = blockIdx.x * 256 + threadIdx.x;
  if (k < NNZb) {
    int n = hidx[k], e = hidx[NNZb + k];
    atomicOr(&hbits[n * 64 + (e >> 5)], 1u << (e & 31));
    atomicOr(&hbitsT[e * 128 + (n >> 5)], 1u << (n & 31));
    hbT[(size_t)e * NN + n] = 0x3F80;            // bf16 1.0
  } else {
    int i = k - NNZb;
    if (i < NN) atomicOr(&abits[i * 128 + (i >> 5)], 1u << (i & 31));
  }
}

// merged: blocks [0,1024) rowdots; [1024,3072) clique
__global__ void k_rowclique(const u16* __restrict__ whg, const u16* __restrict__ x4,
                            const float* __restrict__ ag, const float* __restrict__ wc,
                            float* wh1, float* wh2, float* v,
                            const u32* __restrict__ hbitsT, u32* abits) {
  __shared__ int list[512];
  __shared__ int cnt;
  int tid = threadIdx.x;
  if (blockIdx.x < 1024) {
    int wv = tid >> 6, l = tid & 63;
    int row = blockIdx.x * 4 + wv;
    float s1 = 0, s2 = 0, s3 = 0;
    #pragma unroll
    for (int dd = 0; dd < 4; ++dd) {
      int d = l * 4 + dd;
      float a = from_bf(whg[row * 256 + d]);
      s1 += a * ag[d]; s2 += a * ag[256 + d];
      s3 += from_bf(x4[row * 256 + d]) * wc[d];
    }
    s1 = wredf(s1); s2 = wredf(s2); s3 = wredf(s3);
    if (l == 0) { wh1[row] = s1; wh2[row] = s2; v[row] = s3 * (1.0f / 16.0f); }
  } else {
    int e = blockIdx.x - 1024;
    if (tid == 0) cnt = 0;
    __syncthreads();
    if (tid < 128) {
      u32 w = hbitsT[e * 128 + tid];
      while (w) {
        int b = __ffs(w) - 1;
        int p = atomicAdd(&cnt, 1);
        if (p < 512) list[p] = tid * 32 + b;
        w &= w - 1;
      }
    }
    __syncthreads();
    int c = cnt < 512 ? cnt : 512;
    for (int p = tid; p < c * c; p += 256) {
      int i = list[p / c], j = list[p % c];
      atomicOr(&abits[i * 128 + (j >> 5)], 1u << (j & 31));
    }
  }
}

__global__ void k_exprows(const u32* __restrict__ abits, const float* __restrict__ wh1,
                          const float* __restrict__ wh2, u16* __restrict__ expA,
                          float* rsInv) {
  int i = blockIdx.x, tid = threadIdx.x;
  __shared__ float w2s[NN];
  __shared__ float ssum;
  for (int j = tid; j < NN; j += 256) w2s[j] = wh2[j];
  if (tid == 0) ssum = 0.f;
  __syncthreads();
  float a = wh1[i], lsum = 0.f;
  for (int j = tid; j < NN; j += 256) {
    u32 w = abits[i * 128 + (j >> 5)];
    u16 h = 0;
    if ((w >> (j & 31)) & 1) {
      float z = a + w2s[j];
      float eg = z > 0.f ? z : 0.2f * z;
      h = to_bf(__expf(eg));
      lsum += from_bf(h);
    }
    expA[(size_t)i * NN + j] = h;
  }
  lsum = wredf(lsum);
  if ((tid & 63) == 0) atomicAdd(&ssum, lsum);
  __syncthreads();
  if (tid == 0) rsInv[i] = 1.0f / ssum;
}

__global__ void k_edge_softmax(const u16* __restrict__ g2hT, const u32* __restrict__ hbitsT,
                               const float* __restrict__ v, u16* __restrict__ att1) {
  int e = blockIdx.x, tid = threadIdx.x;
  __shared__ float evals[NN];
  __shared__ u32 hw[128];
  __shared__ float s1s, s2s; __shared__ int cs;
  if (tid == 0) { s1s = 0.f; s2s = 0.f; cs = 0; }
  if (tid < 128) hw[tid] = hbitsT[e * 128 + tid];
  __syncthreads();
  float sum1 = 0.f;
  for (int j = tid; j < NN; j += 256) {
    float ev = __expf(from_bf(g2hT[(size_t)e * NN + j]));
    evals[j] = ev; sum1 += ev;
  }
  float sum2 = 0.f; int cnt = 0;
  if (tid < 128) {
    u32 w = hw[tid]; cnt = __popc(w);
    while (w) { int b = __ffs(w) - 1; sum2 += __expf(v[tid * 32 + b]); w &= w - 1; }
  }
  sum1 = wredf(sum1); sum2 = wredf(sum2); cnt = wredi(cnt);
  if ((tid & 63) == 0) { atomicAdd(&s1s, sum1); atomicAdd(&s2s, sum2); atomicAdd(&cs, cnt); }
  __syncthreads();
  float inv1 = 1.0f / s1s;
  int c = cs;
  float inv2 = c > 0 ? 1.0f / s2s : 0.0f;
  float unif = c > 0 ? 0.0f : (1.0f / (float)NN);
  for (int j = tid; j < NN; j += 256) {
    float t = evals[j] * inv1 + unif;
    if ((hw[j >> 5] >> (j & 31)) & 1) t += __expf(v[j]) * inv2;
    att1[(size_t)e * NN + j] = to_bf(t);
  }
}

__global__ void k_node_softmax(const u16* __restrict__ g2h, const u16* __restrict__ attn2,
                               const u32* __restrict__ hbits, u16* __restrict__ att2hn) {
  int n = blockIdx.x, tid = threadIdx.x;
  __shared__ float ev3[EE], ev4[EE];
  __shared__ u32 hw[64];
  __shared__ float s3s, s4s; __shared__ int cs;
  if (tid == 0) { s3s = 0.f; s4s = 0.f; cs = 0; }
  if (tid < 64) hw[tid] = hbits[n * 64 + tid];
  __syncthreads();
  float s3 = 0.f, s4 = 0.f; int cl = 0;
  for (int e = tid; e < EE; e += 256) {
    float x3 = __expf(from_bf(g2h[(size_t)n * EE + e]));
    ev3[e] = x3; s3 += x3;
    bool m = (hw[e >> 5] >> (e & 31)) & 1;
    float x4 = m ? __expf(from_bf(attn2[(size_t)n * EE + e])) : 0.f;
    ev4[e] = x4; s4 += x4; cl += m;
  }
  s3 = wredf(s3); s4 = wredf(s4); cl = wredi(cl);
  if ((tid & 63) == 0) { atomicAdd(&s3s, s3); atomicAdd(&s4s, s4); atomicAdd(&cs, cl); }
  __syncthreads();
  float inv3 = 1.0f / s3s;
  int c = cs;
  float inv4 = c > 0 ? 1.0f / s4s : 0.0f;
  float unif = c > 0 ? 0.0f : (1.0f / (float)EE);
  for (int e = tid; e < EE; e += 256)
    att2hn[(size_t)n * EE + e] = to_bf(ev3[e] * inv3 + ev4[e] * inv4 + unif);
}

__global__ void k_transpose(const u16* __restrict__ in, u16* __restrict__ out,
                            int R, int C) {
  __shared__ u16 t[32 * 33];
  t32_tile(in, out, R, C, blockIdx.x, blockIdx.y, t);
}

// ---------------- launch ----------------
extern "C" void kernel_launch(void* const* d_in, const int* in_sizes, int n_in,
                              void* d_out, int out_size, void* d_ws, size_t ws_size,
                              hipStream_t stream) {
  (void)in_sizes; (void)n_in; (void)out_size; (void)ws_size;
  const float* x    = (const float*)d_in[0];
  const float* w1   = (const float*)d_in[1];
  const float* w2   = (const float*)d_in[2];
  const float* w3   = (const float*)d_in[3];
  const float* wg   = (const float*)d_in[4];
  const float* ag   = (const float*)d_in[5];
  const float* wc   = (const float*)d_in[6];
  const float* bias = (const float*)d_in[7];
  const int*   hidx = (const int*)d_in[8];
  float* out = (float*)d_out;
  char* ws = (char*)d_ws;

  u32* Hbits   = (u32*)(ws + OFF_HBITS);
  u32* HbitsT  = (u32*)(ws + OFF_HBITST);
  u32* Abits   = (u32*)(ws + OFF_ABITS);
  float* Wh1   = (float*)(ws + OFF_WH1);
  float* Wh2   = (float*)(ws + OFF_WH2);
  float* V     = (float*)(ws + OFF_V);
  float* RsInv = (float*)(ws + OFF_RSINV);
  u16* Wcat    = (u16*)(ws + OFF_WCAT);
  u16* W3b     = Wcat + 196608;
  u16* Xb      = (u16*)(ws + OFF_XB);
  u16* Whg     = (u16*)(ws + OFF_WHG);
  u16* X4att   = (u16*)(ws + OFF_X4ATT);
  u16* Yb      = (u16*)(ws + OFF_YB);
  u16* XwT     = (u16*)(ws + OFF_XWT);     // Fcat = [XwT|WhgTa], contiguous
  u16* WhgTa   = (u16*)(ws + OFF_WHGTA);
  u16* HbT     = (u16*)(ws + OFF_HBT);
  u16* WhgTb   = (u16*)(ws + OFF_WHGTB);
  u16* ExpA    = (u16*)(ws + OFF_EXPA);
  u16* Att1    = (u16*)(ws + OFF_ATT1);
  u16* Att1T   = (u16*)(ws + OFF_ATT1T);
  u16* Att2hn  = (u16*)(ws + OFF_ATT2HN);
  u16* G2h     = (u16*)(ws + OFF_G2H);
  u16* G2hT    = (u16*)(ws + OFF_G2HT);
  u16* Att2hnT = (u16*)(ws + OFF_ATT2HNT);
  u16* Attn2   = (u16*)(ws + OFF_ATTN2);
  float* G1    = (float*)(ws + OFF_G1);
  float* C2    = (float*)(ws + OFF_C2);
  u16* Edge    = (u16*)(ws + OFF_EDGE);
  u16* EdgeT   = (u16*)(ws + OFF_EDGET);   // [EdgeT|Hn2T] = C1 B-cat, contiguous
  u16* Hn2T    = (u16*)(ws + OFF_HN2T);
  u16* Edge2T  = (u16*)(ws + OFF_EDGE2T);

  // 1. casts + zeroing (bits 4 MB, HbT 16 MB)
  k_prep<<<10240, 256, 0, stream>>>(wg, w2, w1, w3, x, Wcat, Xb,
                                    ws + OFF_HBITS, ws + OFF_HBT);
  // 2. incidence bitsets + H^T + A-diagonal
  k_scatter_diag<<<272, 256, 0, stream>>>(hidx, Hbits, HbitsT, HbT, Abits);
  // 3. G0: x @ [wgT|w2T|w1T] -> Whg(+2T) | X4att | XwT(+bias)
  gemm_k<128, 64, 3><<<384, 256, 0, stream>>>(
      Xb, Wcat, 12, 256, EpiG0{Whg, WhgTa, WhgTb, X4att, XwT, bias});
  // 4. rowdots (Wh1,Wh2,V) + clique expansion into Abits
  k_rowclique<<<3072, 256, 0, stream>>>(Whg, X4att, ag, wc, Wh1, Wh2, V,
                                        HbitsT, Abits);
  // 5. expA rows + 1/rowsum
  k_exprows<<<NN, 256, 0, stream>>>(Abits, Wh1, Wh2, ExpA, RsInv);
  // 6. big fused GEMM: attention_g @ [H|Whg] -> G2h + G2hT + G1
  gemm_k<128, 96, 3><<<768, 256, 0, stream>>>(
      ExpA, HbT, 24, NN, EpiBig{RsInv, G2h, G2hT, G1});
  // 7. att1 per edge
  k_edge_softmax<<<EE, 256, 0, stream>>>(G2hT, HbitsT, V, Att1);
  // 8. tri: [EdgeT|Edge2T](+Edge) = Fcat @ att1^T | Yb = X4att@w3^T | Att1->Att1T
  k_tri_edge<<<8576, 256, 0, stream>>>(
      XwT, Att1, EpiEdgeT{EdgeT, Edge2T, Edge},
      X4att, W3b, EpiBf16{Yb, 256},
      Att1, Att1T);
  // 9. dual: C2 = att1^T @ edge2 | attn2 = Yb @ edge^T / temp
  k_dual_attn2<<<640, 256, 0, stream>>>(
      Att1T, Edge2T, EpiF32{C2, 256},
      Yb, Edge, EpiBf16Scale{Attn2, EE, 1.0f / 16.0f});
  // 10. att2hn per node
  k_node_softmax<<<NN, 256, 0, stream>>>(G2h, Attn2, Hbits, Att2hn);
  // 11. Att2hn -> Att2hnT
  k_transpose<<<dim3(64, 128), 256, 0, stream>>>(Att2hn, Att2hnT, NN, EE);
  // 12. hn2T = Whg^T @ att2hn (direct transposed output)
  gemm_k<64, 32, 2><<<256, 256, 0, stream>>>(
      WhgTa, Att2hnT, 64, NN, EpiBf16{Hn2T, EE});
  // 13. C1 = att2hn @ [edge|hn2] with fused relu/elu combine -> d_out
  gemm_k<64, 64, 2><<<512, 256, 0, stream>>>(
      Att2hn, EdgeT, 8, EE, EpiCombine{G1, C2, out});
}